// Round 3
// 456.363 us; speedup vs baseline: 1.0199x; 1.0199x over previous
//
// ---------------------------------------------------------------------------
// THEORY (Round 2 resubmit; rounds 0/1 failed on harness extraction, never ran)
//
// qkv_gemm at 177 us = 582 TF with MfmaUtil 25%, VALUBusy 38%, HBM 13%:
// schedule-bound at the known ~600 TF ceiling of the 128^2-tile
// 2-barrier-per-K-step structure (stage -> vmcnt(0) drain -> barrier ->
// compute chain is ~72% of critical path).
//
// CHANGE: port both GEMMs to the 256^2-tile deep-pipelined schedule
// (T2 LDS-XOR-swizzle + T3 phase-split + T4 counted-vmcnt + T5 setprio):
//   - 512 thr = 8 waves (2Mx4N), per-wave 128x64 out, acc[8][4], BK=32
//   - 4-slot LDS ring (128 KiB), prologue stages 3 tiles, steady-state
//     keeps 2-3 tiles in flight, boundary waits vmcnt(8)/(4)/(0) -- never
//     drains mid-loop
//   - swizzle applied on global SOURCE addr (LDS dest linear, rule 21) and
//     on ds_read addr: 16B-chunk col' = col ^ ((row>>1)&3)
//   - 2 phases/K-tile, each: {ds_read frags | issue 2 GLDS16 for t+3} ->
//     barrier -> lgkmcnt(0) -> sched_barrier -> setprio(1) -> 16 MFMA
//
// PREDICTED DELTAS: qkv_gemm dur 177 -> ~95 us, MfmaUtil 25 -> >=50%,
// SQ_LDS_BANK_CONFLICT 1.26e7 -> <1e6, VGPR 96 -> ~220, LDS 16K -> 128K,
// OccupancyPercent drops (1 block/CU by design). gemm_out ~59 -> ~45 us.
// flash_attn/casts untouched. Total 465 -> ~340-360 us.
// ---------------------------------------------------------------------------
#include <hip/hip_runtime.h>
#include <hip/hip_bf16.h>

using bf16 = __hip_bfloat16;
typedef __attribute__((ext_vector_type(8))) short short8;
typedef __attribute__((ext_vector_type(4))) float floatx4;
typedef __attribute__((ext_vector_type(2))) float floatx2;

#define GLDS16(g, l)                                                        \
  __builtin_amdgcn_global_load_lds(                                         \
      (const __attribute__((address_space(1))) void*)(g),                   \
      (__attribute__((address_space(3))) void*)(l), 16, 0, 0)

#define MFMA16(a, b, c) __builtin_amdgcn_mfma_f32_16x16x32_bf16(a, b, c, 0, 0, 0)

__device__ __forceinline__ short f2b(float x) {
  union { bf16 h; short s; } u;
  u.h = __float2bfloat16(x);
  return u.s;
}
__device__ __forceinline__ void st(float* p, float v) { *p = v; }
__device__ __forceinline__ void st(bf16* p, float v) { *p = __float2bfloat16(v); }

// ---- DPP cross-lane (stays off the LDS pipe) ------------------------------
template <int CTRL>
__device__ __forceinline__ float dpp_f(float x) {
  return __int_as_float(__builtin_amdgcn_update_dpp(
      0, __float_as_int(x), CTRL, 0xF, 0xF, true));
}
__device__ __forceinline__ float red16_max(float x) {
  x = fmaxf(x, dpp_f<0xB1>(x));    // quad_perm xor1
  x = fmaxf(x, dpp_f<0x4E>(x));    // quad_perm xor2
  x = fmaxf(x, dpp_f<0x141>(x));   // row_half_mirror
  x = fmaxf(x, dpp_f<0x140>(x));   // row_mirror
  return x;
}
__device__ __forceinline__ float red16_sum(float x) {
  x += dpp_f<0xB1>(x);
  x += dpp_f<0x4E>(x);
  x += dpp_f<0x141>(x);
  x += dpp_f<0x140>(x);
  return x;
}

// ---------------------------------------------------------------------------
// fp32 -> bf16 cast, 8 elems/thread, coalesced.
// ---------------------------------------------------------------------------
__global__ void cast_kernel(const float* __restrict__ in, bf16* __restrict__ out,
                            long n) {
  long i = ((long)blockIdx.x * blockDim.x + threadIdx.x) * 8;
  if (i >= n) return;
  floatx4 a = *(const floatx4*)(in + i);
  floatx4 b = *(const floatx4*)(in + i + 4);
  short8 r;
  r[0] = f2b(a[0]); r[1] = f2b(a[1]); r[2] = f2b(a[2]); r[3] = f2b(a[3]);
  r[4] = f2b(b[0]); r[5] = f2b(b[1]); r[6] = f2b(b[2]); r[7] = f2b(b[3]);
  *(short8*)(out + i) = r;
}

// ---------------------------------------------------------------------------
// RoPE cos/sin table: tab[s*64+p] = {cos(s*invf(p)), sin(s*invf(p))}.
// ---------------------------------------------------------------------------
__global__ void rope_tab_kernel(floatx2* __restrict__ tab) {
  const int t = blockIdx.x * blockDim.x + threadIdx.x;   // [0, 131072)
  const int s = t >> 6, p = t & 63;
  const float invf = exp2f(-(float)p * (13.287712379549449f / 64.0f));
  float sn, cs;
  sincosf((float)s * invf, &sn, &cs);
  floatx2 e; e[0] = cs; e[1] = sn;
  tab[t] = e;
}

// ---------------------------------------------------------------------------
// 256x256 deep-pipelined GEMM core (T2+T3+T4+T5). See THEORY header.
// ---------------------------------------------------------------------------
__device__ __forceinline__ void gemm_core256(
    const bf16* __restrict__ A, const bf16* __restrict__ B, int K,
    long m0, long n0, bf16* As, bf16* Bs, floatx4 (&acc)[8][4])
{
  const int tid  = threadIdx.x;
  const int wave = tid >> 6;
  const int lane = tid & 63;
  const int quad = lane >> 4;
  const int l16  = lane & 15;
  const int wr = wave >> 2;     // 0..1 -> rows wr*128
  const int wc = wave & 3;      // 0..3 -> cols wc*64

  // staging: chunk c = i*512 + tid; row = c>>2; src col16 = (c&3)^((c>>3)&3)
  long ga[2], gb[2];
  int ldsoff[2];
#pragma unroll
  for (int i = 0; i < 2; i++) {
    const int c = i * 512 + tid;
    const int row = c >> 2;
    const int col = (c & 3) ^ ((c >> 3) & 3);
    ga[i] = (m0 + row) * (long)K + col * 8;
    gb[i] = (n0 + row) * (long)K + col * 8;
    ldsoff[i] = (i * 512 + wave * 64) * 8;   // wave-uniform LDS base (elems)
  }

  // read-side swizzled k-chunk (element offset), constant per thread:
  // rows read are (16*x + l16), so (row>>1)&3 = (l16>>1)&3 for all x.
  const int qs = (quad ^ ((l16 >> 1) & 3)) * 8;

#pragma unroll
  for (int mi = 0; mi < 8; mi++)
#pragma unroll
    for (int ni = 0; ni < 4; ni++) {
      floatx4 z = {0.f, 0.f, 0.f, 0.f};
      acc[mi][ni] = z;
    }

  const int NT = K >> 5;

  // prologue: stage tiles 0,1,2 into slots 0,1,2 (12 loads in flight)
#pragma unroll
  for (int t = 0; t < 3; t++) {
#pragma unroll
    for (int i = 0; i < 2; i++) {
      GLDS16(A + ga[i] + t * 32, As + t * 8192 + ldsoff[i]);
      GLDS16(B + gb[i] + t * 32, Bs + t * 8192 + ldsoff[i]);
    }
  }
  asm volatile("s_waitcnt vmcnt(8)" ::: "memory");   // tile 0 landed
  __builtin_amdgcn_s_barrier();

  for (int t = 0; t < NT; t++) {
    const bf16* Ab = As + (t & 3) * 8192;
    const bf16* Bb = Bs + (t & 3) * 8192;
    const int pf = t + 3;
    bf16* Apf = As + (pf & 3) * 8192;
    bf16* Bpf = Bs + (pf & 3) * 8192;
    const long pfk = (long)pf * 32;
    const bool do_pf = pf < NT;

    // ---------------- phase A: a[0..7], b0, b1 ; prefetch A(t+3) ----------
    short8 a[8], b0, b1;
#pragma unroll
    for (int mi = 0; mi < 8; mi++)
      a[mi] = *(const short8*)(Ab + (wr * 128 + mi * 16 + l16) * 32 + qs);
    b0 = *(const short8*)(Bb + (wc * 64 + 0 * 16 + l16) * 32 + qs);
    b1 = *(const short8*)(Bb + (wc * 64 + 1 * 16 + l16) * 32 + qs);
    if (do_pf) {
      GLDS16(A + ga[0] + pfk, Apf + ldsoff[0]);
      GLDS16(A + ga[1] + pfk, Apf + ldsoff[1]);
    }
    __builtin_amdgcn_s_barrier();
    asm volatile("s_waitcnt lgkmcnt(0)" ::: "memory");
    __builtin_amdgcn_sched_barrier(0);
    __builtin_amdgcn_s_setprio(1);
#pragma unroll
    for (int mi = 0; mi < 8; mi++) {
      acc[mi][0] = MFMA16(a[mi], b0, acc[mi][0]);
      acc[mi][1] = MFMA16(a[mi], b1, acc[mi][1]);
    }
    __builtin_amdgcn_s_setprio(0);
    __builtin_amdgcn_s_barrier();

    // ---------------- phase B: b2, b3 ; prefetch B(t+3) -------------------
    short8 b2 = *(const short8*)(Bb + (wc * 64 + 2 * 16 + l16) * 32 + qs);
    short8 b3 = *(const short8*)(Bb + (wc * 64 + 3 * 16 + l16) * 32 + qs);
    if (do_pf) {
      GLDS16(B + gb[0] + pfk, Bpf + ldsoff[0]);
      GLDS16(B + gb[1] + pfk, Bpf + ldsoff[1]);
    }
    __builtin_amdgcn_s_barrier();
    asm volatile("s_waitcnt lgkmcnt(0)" ::: "memory");
    __builtin_amdgcn_sched_barrier(0);
    __builtin_amdgcn_s_setprio(1);
#pragma unroll
    for (int mi = 0; mi < 8; mi++) {
      acc[mi][2] = MFMA16(a[mi], b2, acc[mi][2]);
      acc[mi][3] = MFMA16(a[mi], b3, acc[mi][3]);
    }
    __builtin_amdgcn_s_setprio(0);

    // boundary: ensure tile t+1 resident before next iter's ds_reads.
    const int staged = (pf < NT) ? pf : (NT - 1);
    const int newer  = staged - t - 1;       // 2 steady, then 1, 0
    if (newer >= 2)       asm volatile("s_waitcnt vmcnt(8)" ::: "memory");
    else if (newer == 1)  asm volatile("s_waitcnt vmcnt(4)" ::: "memory");
    else                  asm volatile("s_waitcnt vmcnt(0)" ::: "memory");
    __builtin_amdgcn_s_barrier();
  }
}

// ---------------------------------------------------------------------------
// Fused QKV projection. grid (M/256, 24): sel = y>>3 picks weight/output,
// n0 = (y&7)*256. sel 0,1 (q,k): RoPE epilogue. sel 2 (v): transposed out.
// ---------------------------------------------------------------------------
__global__ __launch_bounds__(512, 2) void qkv_gemm(
    const bf16* __restrict__ A,
    const bf16* __restrict__ B0, const bf16* __restrict__ B1,
    const bf16* __restrict__ B2,
    bf16* __restrict__ C0, bf16* __restrict__ C1, bf16* __restrict__ Cvt,
    const floatx2* __restrict__ rtab,
    int M, int N, int K)
{
  __shared__ __align__(16) bf16 As[4 * 8192];
  __shared__ __align__(16) bf16 Bs[4 * 8192];

  const int sel = blockIdx.y >> 3;
  const long m0 = (long)blockIdx.x * 256;
  const long n0 = (long)(blockIdx.y & 7) * 256;
  const bf16* B = (sel == 0) ? B0 : ((sel == 1) ? B1 : B2);

  floatx4 acc[8][4];
  gemm_core256(A, B, K, m0, n0, As, Bs, acc);

  const int tid  = threadIdx.x;
  const int wave = tid >> 6;
  const int lane = tid & 63;
  const int quad = lane >> 4;
  const int l16  = lane & 15;
  const int wr = wave >> 2;
  const int wc = wave & 3;

  if (sel < 2) {
    // RoPE epilogue: pairs (2p,2p+1) in adjacent lanes (l16 bit0).
    bf16* C = (sel == 0) ? C0 : C1;
    const float sgn = (l16 & 1) ? 1.0f : -1.0f;
#pragma unroll
    for (int ni = 0; ni < 4; ni++) {
      const int n = (int)n0 + wc * 64 + ni * 16 + l16;   // h*128 + d
      const int p = (n & 127) >> 1;
#pragma unroll
      for (int mi = 0; mi < 8; mi++) {
        floatx4 v = acc[mi][ni];
        const int mbase = (int)m0 + wr * 128 + mi * 16 + quad * 4;
#pragma unroll
        for (int r = 0; r < 4; r++) {
          const int spos = (mbase + r) & 2047;
          const floatx2 cssn = rtab[spos * 64 + p];
          const float pv = dpp_f<0xB1>(v[r]);       // pair partner
          const float outv = v[r] * cssn[0] + pv * (sgn * cssn[1]);
          st(&C[(long)(mbase + r) * N + n], outv);
        }
      }
    }
  } else {
    // transposed V epilogue: v_t[((b*16+h)*128+d)*2048 + s], 4 s packed
#pragma unroll
    for (int ni = 0; ni < 4; ni++) {
      const int n = (int)n0 + wc * 64 + ni * 16 + l16;   // h*128 + d
      const int hh = n >> 7, d = n & 127;
#pragma unroll
      for (int mi = 0; mi < 8; mi++) {
        floatx4 v = acc[mi][ni];
        const int m = (int)m0 + wr * 128 + mi * 16 + quad * 4;
        const int bb = m >> 11, s = m & 2047;
        unsigned long long pk =
            (unsigned long long)(unsigned short)f2b(v[0]) |
            ((unsigned long long)(unsigned short)f2b(v[1]) << 16) |
            ((unsigned long long)(unsigned short)f2b(v[2]) << 32) |
            ((unsigned long long)(unsigned short)f2b(v[3]) << 48);
        *(unsigned long long*)(Cvt + ((long)((bb * 16 + hh) * 128 + d)) * 2048 + s) = pk;
      }
    }
  }
}

// ---------------------------------------------------------------------------
// Final projection GEMM (bf16 x bf16 -> fp32 out), same 256x256 core.
// ---------------------------------------------------------------------------
__global__ __launch_bounds__(512, 2) void gemm_out(
    const bf16* __restrict__ A, const bf16* __restrict__ B,
    float* __restrict__ C, int M, int N, int K)
{
  __shared__ __align__(16) bf16 As[4 * 8192];
  __shared__ __align__(16) bf16 Bs[4 * 8192];
  const long m0 = (long)blockIdx.x * 256;
  const long n0 = (long)blockIdx.y * 256;

  floatx4 acc[8][4];
  gemm_core256(A, B, K, m0, n0, As, Bs, acc);

  const int tid  = threadIdx.x;
  const int wave = tid >> 6;
  const int lane = tid & 63;
  const int quad = lane >> 4;
  const int l16  = lane & 15;
  const int wr = wave >> 2;
  const int wc = wave & 3;

#pragma unroll
  for (int mi = 0; mi < 8; mi++)
#pragma unroll
    for (int ni = 0; ni < 4; ni++) {
      floatx4 v = acc[mi][ni];
      const long row = m0 + wr * 128 + mi * 16 + quad * 4;
      const long col = n0 + wc * 64 + ni * 16 + l16;
#pragma unroll
      for (int r = 0; r < 4; r++)
        C[(row + r) * (long)N + col] = v[r];
    }
}

// ---------------------------------------------------------------------------
// Causal flash attention (unchanged this round).
// ---------------------------------------------------------------------------
#define NEG_BIG (-30000.0f)

__global__ __launch_bounds__(256) void flash_attn(
    const bf16* __restrict__ q, const bf16* __restrict__ k,
    const bf16* __restrict__ vt, bf16* __restrict__ o, int S)
{
  __shared__ bf16 Ks[64 * 136];      // K tile row-major, stride 136
  __shared__ bf16 Vt[128 * 72];      // V^T tile: [d][kv], stride 72
  __shared__ bf16 Ps[4][32 * 72];    // per-wave P scratch, stride 72

  const int tid  = threadIdx.x;
  const int wave = tid >> 6;
  const int lane = tid & 63;
  const int quad = lane >> 4;
  const int l16  = lane & 15;

  const int bh = blockIdx.x;
  const int b  = bh >> 4, h = bh & 15;
  const int q0 = ((int)gridDim.y - 1 - (int)blockIdx.y) * 128;  // heavy first

  const bf16* Qb = q + ((long)b * S * 16 + h) * 128;
  const bf16* Kb = k + ((long)b * S * 16 + h) * 128;
  const bf16* Vg = vt + (long)bh * 128 * S;       // [d][s]
  bf16*       Ob = o + ((long)b * S * 16 + h) * 128;

  int kr[4], kc[4], vr[4], vc[4];
#pragma unroll
  for (int it = 0; it < 4; it++) {
    const int c = tid + it * 256;
    kr[it] = c >> 4;  kc[it] = (c & 15) * 8;   // K: 64 rows x 128 d
    vr[it] = c >> 3;  vc[it] = (c & 7) * 8;    // V^T: 128 d x 64 kv
  }

  short8 aq[2][4];
#pragma unroll
  for (int mi = 0; mi < 2; mi++)
#pragma unroll
    for (int kt = 0; kt < 4; kt++)
      aq[mi][kt] = *(const short8*)(
          Qb + (long)(q0 + wave * 32 + mi * 16 + l16) * 2048 + kt * 32 + quad * 8);

  float m_i[2][4], l_i[2][4];
  floatx4 oacc[2][8];
  const floatx4 zero4 = {0.f, 0.f, 0.f, 0.f};
#pragma unroll
  for (int mi = 0; mi < 2; mi++) {
#pragma unroll
    for (int r = 0; r < 4; r++) { m_i[mi][r] = NEG_BIG; l_i[mi][r] = 0.f; }
#pragma unroll
    for (int dt = 0; dt < 8; dt++) oacc[mi][dt] = zero4;
  }

  const float SCL2 = 0.08838834764831845f * 1.4426950408889634f;  // scale*log2e
  const int wrow0 = q0 + wave * 32;
  const int last  = q0 + 64;

  short8 kreg[4], vreg[4];
#pragma unroll
  for (int it = 0; it < 4; it++) {
    kreg[it] = *(const short8*)(Kb + (long)kr[it] * 2048 + kc[it]);
    vreg[it] = *(const short8*)(Vg + (long)vr[it] * S + vc[it]);
  }

  for (int kt0 = 0; kt0 <= last; kt0 += 64) {
    __syncthreads();

#pragma unroll
    for (int it = 0; it < 4; it++) {
      *(short8*)(Ks + kr[it] * 136 + kc[it]) = kreg[it];
      *(short8*)(Vt + vr[it] * 72 + vc[it]) = vreg[it];
    }
    __syncthreads();

    if (kt0 < last) {
      const int n0 = kt0 + 64;
#pragma unroll
      for (int it = 0; it < 4; it++) {
        kreg[it] = *(const short8*)(Kb + (long)(n0 + kr[it]) * 2048 + kc[it]);
        vreg[it] = *(const short8*)(Vg + (long)vr[it] * S + n0 + vc[it]);
      }
    }

    if (kt0 <= wrow0 + 31) {
      floatx4 sc[2][4];
#pragma unroll
      for (int mi = 0; mi < 2; mi++)
#pragma unroll
        for (int nt = 0; nt < 4; nt++) sc[mi][nt] = zero4;
#pragma unroll
      for (int nt = 0; nt < 4; nt++)
#pragma unroll
        for (int kt = 0; kt < 4; kt++) {
          short8 bk = *(const short8*)(Ks + (nt * 16 + l16) * 136 + kt * 32 + quad * 8);
          sc[0][nt] = __builtin_amdgcn_mfma_f32_16x16x32_bf16(aq[0][kt], bk, sc[0][nt], 0, 0, 0);
          sc[1][nt] = __builtin_amdgcn_mfma_f32_16x16x32_bf16(aq[1][kt], bk, sc[1][nt], 0, 0, 0);
        }

      const bool needmask = (kt0 + 63 > wrow0);
      float alpha[2][4];
#pragma unroll
      for (int mi = 0; mi < 2; mi++) {
#pragma unroll
        for (int r = 0; r < 4; r++) {
          const int qr = wrow0 + mi * 16 + quad * 4 + r;
          float mx = NEG_BIG;
          if (needmask) {
#pragma unroll
            for (int nt = 0; nt < 4; nt++) {
              const int kc2 = kt0 + nt * 16 + l16;
              float vsc = sc[mi][nt][r] * SCL2;
              vsc = (kc2 <= qr) ? vsc : NEG_BIG;
              sc[mi][nt][r] = vsc;
              mx = fmaxf(mx, vsc);
            }
          } else {
#pragma unroll
            for (int nt = 0; nt < 4; nt++) {
              float vsc = sc[mi][nt][r] * SCL2;
              sc[mi][nt][r] = vsc;
              mx = fmaxf(mx, vsc);
            }
          }
          mx = red16_max(mx);
          const float mnew = fmaxf(m_i[mi][r], mx);

          alpha[mi][r] = exp2f(m_i[mi][r] - mnew);
          float rs = 0.f;
#pragma unroll
          for (int nt = 0; nt < 4; nt++) {
            float p = exp2f(sc[mi][nt][r] - mnew);
            sc[mi][nt][r] = p;
            rs += p;
          }
          rs = red16_sum(rs);
          l_i[mi][r] = l_i[mi][r] * alpha[mi][r] + rs;
          m_i[mi][r] = mnew;
        }
      }

#pragma unroll
      for (int mi = 0; mi < 2; mi++)
#pragma unroll
        for (int nt = 0; nt < 4; nt++)
#pragma unroll
          for (int r = 0; r < 4; r++)
            Ps[wave][(mi * 16 + quad * 4 + r) * 72 + nt * 16 + l16] =
                __float2bfloat16(sc[mi][nt][r]);

#pragma unroll
      for (int mi = 0; mi < 2; mi++)
#pragma unroll
        for (int dt = 0; dt < 8; dt++)
#pragma unroll
          for (int r = 0; r < 4; r++)
            oacc[mi][dt][r] *= alpha[mi][r];

#pragma unroll
      for (int ks = 0; ks < 2; ks++) {
        short8 ap0 = *(const short8*)(&Ps[wave][(l16) * 72 + ks * 32 + quad * 8]);
        short8 ap1 = *(const short8*)(&Ps[wave][(16 + l16) * 72 + ks * 32 + quad * 8]);
#pragma unroll
        for (int dt = 0; dt < 8; dt++) {
          short8 bv = *(const short8*)(Vt + (dt * 16 + l16) * 72 + ks * 32 + quad * 8);
          oacc[0][dt] = __builtin_amdgcn_mfma_f32_16x16x32_bf16(ap0, bv, oacc[0][dt], 0, 0, 0);
          oacc[1][dt] = __builtin_amdgcn_mfma_f32_16x16x32_bf16(ap1, bv, oacc[1][dt], 0, 0, 0);
        }
      }
    }
  }

#pragma unroll
  for (int mi = 0; mi < 2; mi++)
#pragma unroll
    for (int r = 0; r < 4; r++) {
      const float inv = 1.0f / l_i[mi][r];
      const long s = q0 + wave * 32 + mi * 16 + quad * 4 + r;
#pragma unroll
      for (int dt = 0; dt < 8; dt++)
        Ob[s * 2048 + dt * 16 + l16] = __float2bfloat16(oacc[mi][dt][r] * inv);
    }
}

// ---------------------------------------------------------------------------
extern "C" void kernel_launch(void* const* d_in, const int* in_sizes, int n_in,
                              void* d_out, int out_size, void* d_ws, size_t ws_size,
                              hipStream_t stream) {
  const float* x  = (const float*)d_in[0];
  const float* wq = (const float*)d_in[1];
  const float* wk = (const float*)d_in[2];
  const float* wv = (const float*)d_in[3];
  const float* wo = (const float*)d_in[4];
  float* out = (float*)d_out;

  const int B = 2, S = 2048, D = 2048, H = 16;
  const int M = B * S;                    // 4096
  const long tsz = (long)M * D;           // 8.39M elems
  const long wsz = (long)D * D;           // 4.19M elems

  if (ws_size < 4 * (size_t)tsz * sizeof(bf16)) return;   // 67 MB

  bf16* qb  = (bf16*)d_ws;
  bf16* kb  = qb + tsz;
  bf16* vtb = kb + tsz;                   // transposed V: [b][h][d][s]
  bf16* ab  = vtb + tsz;

  // d_out as scratch: xb (tsz) + wq' (wsz) + wk' (wsz) = exactly out bytes.
  bf16* xb  = (bf16*)d_out;
  bf16* wqb = xb + tsz;
  bf16* wkb = wqb + wsz;
  bf16* wvb = ab;                         // front half of ab (dead until flash)
  floatx2* rtab = (floatx2*)(ab + wsz);   // 1 MB rope table in ab's back half
  bf16* wob = qb;                         // qb dead after flash

  cast_kernel<<<(int)(tsz / 8 / 256), 256, 0, stream>>>(x,  xb,  tsz);
  cast_kernel<<<(int)(wsz / 8 / 256), 256, 0, stream>>>(wq, wqb, wsz);
  cast_kernel<<<(int)(wsz / 8 / 256), 256, 0, stream>>>(wk, wkb, wsz);
  cast_kernel<<<(int)(wsz / 8 / 256), 256, 0, stream>>>(wv, wvb, wsz);
  rope_tab_kernel<<<(S * 64) / 256, 256, 0, stream>>>(rtab);

  qkv_gemm<<<dim3(M / 256, 24), 512, 0, stream>>>(
      xb, wqb, wkb, wvb, qb, kb, vtb, rtab, M, D, D);

  flash_attn<<<dim3(B * H, S / 128), 256, 0, stream>>>(qb, kb, vtb, ab, S);

  cast_kernel<<<(int)(wsz / 8 / 256), 256, 0, stream>>>(wo, wob, wsz);
  gemm_out<<<dim3(M / 256, D / 256), 512, 0, stream>>>(ab, wob, out, M, D, D);
}

// Round 4
// 425.294 us; speedup vs baseline: 1.0944x; 1.0731x over previous
//
// ---------------------------------------------------------------------------
// THEORY (Round 4)
// R3 result: 256^2 core lifted qkv per-FLOP rate (582->669 TF, conflicts->0)
// but grid quantization wasted it: qkv 384 blocks = 1.5 rounds (2nd half-idle),
// gemm_out 128 blocks = HALF the CUs idle (regressed ~59->~100 us).
// Phase A was also LDS-heavy (10 ds_reads) vs B (2) -> serialized vs MFMA.
//
// CHANGE: retile both GEMMs to BM=128 x BN=256, BK=32 (same ring + swizzle +
// counted vmcnt + setprio machinery, now proven correct/conflict-free):
//   - 512 thr = 8 waves (2M x 4N), per-wave 64x64, acc[4][4]
//   - one balanced phase per K-tile: 8 ds_reads (4A+4B), 3 gloads, 16 MFMA
//   - LDS ring 4 slots x (8KB A + 16KB B) = 96 KB
//   - qkv grid 32x24 = 768 blocks = 3 FULL rounds; gemm_out 32x8 = 256 = 1 round
// PREDICTED: qkv 154 -> ~115-125 us (MfmaUtil 28 -> 36-40%), gemm_out
// ~100 -> ~45-55 us, conflicts ~0, total 456 -> ~350-375 us.
// ---------------------------------------------------------------------------
#include <hip/hip_runtime.h>
#include <hip/hip_bf16.h>

using bf16 = __hip_bfloat16;
typedef __attribute__((ext_vector_type(8))) short short8;
typedef __attribute__((ext_vector_type(4))) float floatx4;
typedef __attribute__((ext_vector_type(2))) float floatx2;

#define GLDS16(g, l)                                                        \
  __builtin_amdgcn_global_load_lds(                                         \
      (const __attribute__((address_space(1))) void*)(g),                   \
      (__attribute__((address_space(3))) void*)(l), 16, 0, 0)

#define MFMA16(a, b, c) __builtin_amdgcn_mfma_f32_16x16x32_bf16(a, b, c, 0, 0, 0)

__device__ __forceinline__ short f2b(float x) {
  union { bf16 h; short s; } u;
  u.h = __float2bfloat16(x);
  return u.s;
}
__device__ __forceinline__ void st(float* p, float v) { *p = v; }
__device__ __forceinline__ void st(bf16* p, float v) { *p = __float2bfloat16(v); }

// ---- DPP cross-lane (stays off the LDS pipe) ------------------------------
template <int CTRL>
__device__ __forceinline__ float dpp_f(float x) {
  return __int_as_float(__builtin_amdgcn_update_dpp(
      0, __float_as_int(x), CTRL, 0xF, 0xF, true));
}
__device__ __forceinline__ float red16_max(float x) {
  x = fmaxf(x, dpp_f<0xB1>(x));    // quad_perm xor1
  x = fmaxf(x, dpp_f<0x4E>(x));    // quad_perm xor2
  x = fmaxf(x, dpp_f<0x141>(x));   // row_half_mirror
  x = fmaxf(x, dpp_f<0x140>(x));   // row_mirror
  return x;
}
__device__ __forceinline__ float red16_sum(float x) {
  x += dpp_f<0xB1>(x);
  x += dpp_f<0x4E>(x);
  x += dpp_f<0x141>(x);
  x += dpp_f<0x140>(x);
  return x;
}

// ---------------------------------------------------------------------------
// fp32 -> bf16 cast, 8 elems/thread, coalesced.
// ---------------------------------------------------------------------------
__global__ void cast_kernel(const float* __restrict__ in, bf16* __restrict__ out,
                            long n) {
  long i = ((long)blockIdx.x * blockDim.x + threadIdx.x) * 8;
  if (i >= n) return;
  floatx4 a = *(const floatx4*)(in + i);
  floatx4 b = *(const floatx4*)(in + i + 4);
  short8 r;
  r[0] = f2b(a[0]); r[1] = f2b(a[1]); r[2] = f2b(a[2]); r[3] = f2b(a[3]);
  r[4] = f2b(b[0]); r[5] = f2b(b[1]); r[6] = f2b(b[2]); r[7] = f2b(b[3]);
  *(short8*)(out + i) = r;
}

// ---------------------------------------------------------------------------
// RoPE cos/sin table: tab[s*64+p] = {cos(s*invf(p)), sin(s*invf(p))}.
// ---------------------------------------------------------------------------
__global__ void rope_tab_kernel(floatx2* __restrict__ tab) {
  const int t = blockIdx.x * blockDim.x + threadIdx.x;   // [0, 131072)
  const int s = t >> 6, p = t & 63;
  const float invf = exp2f(-(float)p * (13.287712379549449f / 64.0f));
  float sn, cs;
  sincosf((float)s * invf, &sn, &cs);
  floatx2 e; e[0] = cs; e[1] = sn;
  tab[t] = e;
}

// ---------------------------------------------------------------------------
// 128x256 deep-pipelined GEMM core.
//   512 thr = 8 waves (2M x 4N), per-wave 64x64 out, acc[4][4], BK=32.
//   LDS ring: 4 slots x {A:128x32 (4096 el), B:256x32 (8192 el)} = 96 KiB.
//   Per K-tile: 8 ds_read_b128 (4A+4B) | 3 GLDS16 (t+3) -> barrier ->
//   lgkmcnt(0) -> setprio(1) -> 16 MFMA -> counted vmcnt(6/3/0) -> barrier.
//   Swizzle: 16B-chunk col' = col ^ ((row>>1)&3) on global SOURCE addr
//   (LDS dest linear, rule 21) and on ds_read addr (conflicts measured 0).
// ---------------------------------------------------------------------------
__device__ __forceinline__ void gemm_core(
    const bf16* __restrict__ A, const bf16* __restrict__ B, int K,
    long m0, long n0, bf16* As, bf16* Bs, floatx4 (&acc)[4][4])
{
  const int tid  = threadIdx.x;
  const int wave = tid >> 6;
  const int lane = tid & 63;
  const int quad = lane >> 4;
  const int l16  = lane & 15;
  const int wr = wave >> 2;     // 0..1 -> rows wr*64
  const int wc = wave & 3;      // 0..3 -> cols wc*64

  // A staging: 512 chunks (128 rows x 4), 1 chunk/thread.
  // B staging: 1024 chunks (256 rows x 4), 2 chunks/thread.
  const int arow = tid >> 2;
  const int acol = (tid & 3) ^ ((tid >> 3) & 3);
  const long gaoff = (m0 + arow) * (long)K + acol * 8;
  const int alds = wave * 512;              // + lane*8 implicit (elems)
  long gb[2];
  int blds[2];
#pragma unroll
  for (int i = 0; i < 2; i++) {
    const int c = i * 512 + tid;
    const int row = c >> 2;
    const int col = (c & 3) ^ ((c >> 3) & 3);
    gb[i] = (n0 + row) * (long)K + col * 8;
    blds[i] = (i * 512 + wave * 64) * 8;
  }

  // read-side swizzled k-chunk (elem offset): rows read are 16*x + l16,
  // so (row>>1)&3 = (l16>>1)&3 independent of x.
  const int qs = (quad ^ ((l16 >> 1) & 3)) * 8;

#pragma unroll
  for (int mi = 0; mi < 4; mi++)
#pragma unroll
    for (int ni = 0; ni < 4; ni++) {
      floatx4 z = {0.f, 0.f, 0.f, 0.f};
      acc[mi][ni] = z;
    }

  const int NT = K >> 5;

  // prologue: stage tiles 0,1,2 (3 loads each: A, B0, B1)
#pragma unroll
  for (int t = 0; t < 3; t++) {
    GLDS16(A + gaoff + t * 32, As + t * 4096 + alds);
    GLDS16(B + gb[0] + t * 32, Bs + t * 8192 + blds[0]);
    GLDS16(B + gb[1] + t * 32, Bs + t * 8192 + blds[1]);
  }
  asm volatile("s_waitcnt vmcnt(6)" ::: "memory");   // tile 0 landed
  __builtin_amdgcn_s_barrier();

  for (int t = 0; t < NT; t++) {
    const bf16* Ab = As + (t & 3) * 4096;
    const bf16* Bb = Bs + (t & 3) * 8192;
    const int pf = t + 3;

    // balanced phase: 8 ds_reads + 3 gloads, then 16 MFMA
    short8 a[4], b[4];
#pragma unroll
    for (int mi = 0; mi < 4; mi++)
      a[mi] = *(const short8*)(Ab + (wr * 64 + mi * 16 + l16) * 32 + qs);
#pragma unroll
    for (int ni = 0; ni < 4; ni++)
      b[ni] = *(const short8*)(Bb + (wc * 64 + ni * 16 + l16) * 32 + qs);

    if (pf < NT) {
      bf16* Apf = As + (pf & 3) * 4096;
      bf16* Bpf = Bs + (pf & 3) * 8192;
      const long pfk = (long)pf * 32;
      GLDS16(A + gaoff + pfk, Apf + alds);
      GLDS16(B + gb[0] + pfk, Bpf + blds[0]);
      GLDS16(B + gb[1] + pfk, Bpf + blds[1]);
    }
    __builtin_amdgcn_s_barrier();
    asm volatile("s_waitcnt lgkmcnt(0)" ::: "memory");
    __builtin_amdgcn_sched_barrier(0);
    __builtin_amdgcn_s_setprio(1);
#pragma unroll
    for (int mi = 0; mi < 4; mi++)
#pragma unroll
      for (int ni = 0; ni < 4; ni++)
        acc[mi][ni] = MFMA16(a[mi], b[ni], acc[mi][ni]);
    __builtin_amdgcn_s_setprio(0);

    // boundary: ensure tile t+1 resident before next iter's ds_reads.
    const int staged = (pf < NT) ? pf : (NT - 1);
    const int newer  = staged - t - 1;       // 2 steady, then 1, 0
    if (newer >= 2)       asm volatile("s_waitcnt vmcnt(6)" ::: "memory");
    else if (newer == 1)  asm volatile("s_waitcnt vmcnt(3)" ::: "memory");
    else                  asm volatile("s_waitcnt vmcnt(0)" ::: "memory");
    __builtin_amdgcn_s_barrier();
  }
}

// ---------------------------------------------------------------------------
// Fused QKV projection. grid (M/128, 24): sel = y>>3 picks weight/output,
// n0 = (y&7)*256. sel 0,1 (q,k): RoPE epilogue. sel 2 (v): transposed out.
// 768 blocks = exactly 3 full rounds of 256 CUs.
// ---------------------------------------------------------------------------
__global__ __launch_bounds__(512, 2) void qkv_gemm(
    const bf16* __restrict__ A,
    const bf16* __restrict__ B0, const bf16* __restrict__ B1,
    const bf16* __restrict__ B2,
    bf16* __restrict__ C0, bf16* __restrict__ C1, bf16* __restrict__ Cvt,
    const floatx2* __restrict__ rtab,
    int M, int N, int K)
{
  __shared__ __align__(16) bf16 As[4 * 4096];
  __shared__ __align__(16) bf16 Bs[4 * 8192];

  const int sel = blockIdx.y >> 3;
  const long m0 = (long)blockIdx.x * 128;
  const long n0 = (long)(blockIdx.y & 7) * 256;
  const bf16* B = (sel == 0) ? B0 : ((sel == 1) ? B1 : B2);

  floatx4 acc[4][4];
  gemm_core(A, B, K, m0, n0, As, Bs, acc);

  const int tid  = threadIdx.x;
  const int wave = tid >> 6;
  const int lane = tid & 63;
  const int quad = lane >> 4;
  const int l16  = lane & 15;
  const int wr = wave >> 2;
  const int wc = wave & 3;

  if (sel < 2) {
    // RoPE epilogue: pairs (2p,2p+1) in adjacent lanes (l16 bit0).
    bf16* C = (sel == 0) ? C0 : C1;
    const float sgn = (l16 & 1) ? 1.0f : -1.0f;
#pragma unroll
    for (int ni = 0; ni < 4; ni++) {
      const int n = (int)n0 + wc * 64 + ni * 16 + l16;   // h*128 + d
      const int p = (n & 127) >> 1;
#pragma unroll
      for (int mi = 0; mi < 4; mi++) {
        floatx4 v = acc[mi][ni];
        const int mbase = (int)m0 + wr * 64 + mi * 16 + quad * 4;
#pragma unroll
        for (int r = 0; r < 4; r++) {
          const int spos = (mbase + r) & 2047;
          const floatx2 cssn = rtab[spos * 64 + p];
          const float pv = dpp_f<0xB1>(v[r]);       // pair partner
          const float outv = v[r] * cssn[0] + pv * (sgn * cssn[1]);
          st(&C[(long)(mbase + r) * N + n], outv);
        }
      }
    }
  } else {
    // transposed V epilogue: v_t[((b*16+h)*128+d)*2048 + s], 4 s packed
#pragma unroll
    for (int ni = 0; ni < 4; ni++) {
      const int n = (int)n0 + wc * 64 + ni * 16 + l16;   // h*128 + d
      const int hh = n >> 7, d = n & 127;
#pragma unroll
      for (int mi = 0; mi < 4; mi++) {
        floatx4 v = acc[mi][ni];
        const int m = (int)m0 + wr * 64 + mi * 16 + quad * 4;
        const int bb = m >> 11, s = m & 2047;
        unsigned long long pk =
            (unsigned long long)(unsigned short)f2b(v[0]) |
            ((unsigned long long)(unsigned short)f2b(v[1]) << 16) |
            ((unsigned long long)(unsigned short)f2b(v[2]) << 32) |
            ((unsigned long long)(unsigned short)f2b(v[3]) << 48);
        *(unsigned long long*)(Cvt + ((long)((bb * 16 + hh) * 128 + d)) * 2048 + s) = pk;
      }
    }
  }
}

// ---------------------------------------------------------------------------
// Final projection GEMM (bf16 x bf16 -> fp32 out), same 128x256 core.
// grid 32x8 = 256 blocks = exactly 1 full round.
// ---------------------------------------------------------------------------
__global__ __launch_bounds__(512, 2) void gemm_out(
    const bf16* __restrict__ A, const bf16* __restrict__ B,
    float* __restrict__ C, int M, int N, int K)
{
  __shared__ __align__(16) bf16 As[4 * 4096];
  __shared__ __align__(16) bf16 Bs[4 * 8192];
  const long m0 = (long)blockIdx.x * 128;
  const long n0 = (long)blockIdx.y * 256;

  floatx4 acc[4][4];
  gemm_core(A, B, K, m0, n0, As, Bs, acc);

  const int tid  = threadIdx.x;
  const int wave = tid >> 6;
  const int lane = tid & 63;
  const int quad = lane >> 4;
  const int l16  = lane & 15;
  const int wr = wave >> 2;
  const int wc = wave & 3;

#pragma unroll
  for (int mi = 0; mi < 4; mi++)
#pragma unroll
    for (int ni = 0; ni < 4; ni++) {
      floatx4 v = acc[mi][ni];
      const long row = m0 + wr * 64 + mi * 16 + quad * 4;
      const long col = n0 + wc * 64 + ni * 16 + l16;
#pragma unroll
      for (int r = 0; r < 4; r++)
        C[(row + r) * (long)N + col] = v[r];
    }
}

// ---------------------------------------------------------------------------
// Causal flash attention (unchanged this round).
// ---------------------------------------------------------------------------
#define NEG_BIG (-30000.0f)

__global__ __launch_bounds__(256) void flash_attn(
    const bf16* __restrict__ q, const bf16* __restrict__ k,
    const bf16* __restrict__ vt, bf16* __restrict__ o, int S)
{
  __shared__ bf16 Ks[64 * 136];      // K tile row-major, stride 136
  __shared__ bf16 Vt[128 * 72];      // V^T tile: [d][kv], stride 72
  __shared__ bf16 Ps[4][32 * 72];    // per-wave P scratch, stride 72

  const int tid  = threadIdx.x;
  const int wave = tid >> 6;
  const int lane = tid & 63;
  const int quad = lane >> 4;
  const int l16  = lane & 15;

  const int bh = blockIdx.x;
  const int b  = bh >> 4, h = bh & 15;
  const int q0 = ((int)gridDim.y - 1 - (int)blockIdx.y) * 128;  // heavy first

  const bf16* Qb = q + ((long)b * S * 16 + h) * 128;
  const bf16* Kb = k + ((long)b * S * 16 + h) * 128;
  const bf16* Vg = vt + (long)bh * 128 * S;       // [d][s]
  bf16*       Ob = o + ((long)b * S * 16 + h) * 128;

  int kr[4], kc[4], vr[4], vc[4];
#pragma unroll
  for (int it = 0; it < 4; it++) {
    const int c = tid + it * 256;
    kr[it] = c >> 4;  kc[it] = (c & 15) * 8;   // K: 64 rows x 128 d
    vr[it] = c >> 3;  vc[it] = (c & 7) * 8;    // V^T: 128 d x 64 kv
  }

  short8 aq[2][4];
#pragma unroll
  for (int mi = 0; mi < 2; mi++)
#pragma unroll
    for (int kt = 0; kt < 4; kt++)
      aq[mi][kt] = *(const short8*)(
          Qb + (long)(q0 + wave * 32 + mi * 16 + l16) * 2048 + kt * 32 + quad * 8);

  float m_i[2][4], l_i[2][4];
  floatx4 oacc[2][8];
  const floatx4 zero4 = {0.f, 0.f, 0.f, 0.f};
#pragma unroll
  for (int mi = 0; mi < 2; mi++) {
#pragma unroll
    for (int r = 0; r < 4; r++) { m_i[mi][r] = NEG_BIG; l_i[mi][r] = 0.f; }
#pragma unroll
    for (int dt = 0; dt < 8; dt++) oacc[mi][dt] = zero4;
  }

  const float SCL2 = 0.08838834764831845f * 1.4426950408889634f;  // scale*log2e
  const int wrow0 = q0 + wave * 32;
  const int last  = q0 + 64;

  short8 kreg[4], vreg[4];
#pragma unroll
  for (int it = 0; it < 4; it++) {
    kreg[it] = *(const short8*)(Kb + (long)kr[it] * 2048 + kc[it]);
    vreg[it] = *(const short8*)(Vg + (long)vr[it] * S + vc[it]);
  }

  for (int kt0 = 0; kt0 <= last; kt0 += 64) {
    __syncthreads();

#pragma unroll
    for (int it = 0; it < 4; it++) {
      *(short8*)(Ks + kr[it] * 136 + kc[it]) = kreg[it];
      *(short8*)(Vt + vr[it] * 72 + vc[it]) = vreg[it];
    }
    __syncthreads();

    if (kt0 < last) {
      const int n0 = kt0 + 64;
#pragma unroll
      for (int it = 0; it < 4; it++) {
        kreg[it] = *(const short8*)(Kb + (long)(n0 + kr[it]) * 2048 + kc[it]);
        vreg[it] = *(const short8*)(Vg + (long)vr[it] * S + n0 + vc[it]);
      }
    }

    if (kt0 <= wrow0 + 31) {
      floatx4 sc[2][4];
#pragma unroll
      for (int mi = 0; mi < 2; mi++)
#pragma unroll
        for (int nt = 0; nt < 4; nt++) sc[mi][nt] = zero4;
#pragma unroll
      for (int nt = 0; nt < 4; nt++)
#pragma unroll
        for (int kt = 0; kt < 4; kt++) {
          short8 bk = *(const short8*)(Ks + (nt * 16 + l16) * 136 + kt * 32 + quad * 8);
          sc[0][nt] = __builtin_amdgcn_mfma_f32_16x16x32_bf16(aq[0][kt], bk, sc[0][nt], 0, 0, 0);
          sc[1][nt] = __builtin_amdgcn_mfma_f32_16x16x32_bf16(aq[1][kt], bk, sc[1][nt], 0, 0, 0);
        }

      const bool needmask = (kt0 + 63 > wrow0);
      float alpha[2][4];
#pragma unroll
      for (int mi = 0; mi < 2; mi++) {
#pragma unroll
        for (int r = 0; r < 4; r++) {
          const int qr = wrow0 + mi * 16 + quad * 4 + r;
          float mx = NEG_BIG;
          if (needmask) {
#pragma unroll
            for (int nt = 0; nt < 4; nt++) {
              const int kc2 = kt0 + nt * 16 + l16;
              float vsc = sc[mi][nt][r] * SCL2;
              vsc = (kc2 <= qr) ? vsc : NEG_BIG;
              sc[mi][nt][r] = vsc;
              mx = fmaxf(mx, vsc);
            }
          } else {
#pragma unroll
            for (int nt = 0; nt < 4; nt++) {
              float vsc = sc[mi][nt][r] * SCL2;
              sc[mi][nt][r] = vsc;
              mx = fmaxf(mx, vsc);
            }
          }
          mx = red16_max(mx);
          const float mnew = fmaxf(m_i[mi][r], mx);

          alpha[mi][r] = exp2f(m_i[mi][r] - mnew);
          float rs = 0.f;
#pragma unroll
          for (int nt = 0; nt < 4; nt++) {
            float p = exp2f(sc[mi][nt][r] - mnew);
            sc[mi][nt][r] = p;
            rs += p;
          }
          rs = red16_sum(rs);
          l_i[mi][r] = l_i[mi][r] * alpha[mi][r] + rs;
          m_i[mi][r] = mnew;
        }
      }

#pragma unroll
      for (int mi = 0; mi < 2; mi++)
#pragma unroll
        for (int nt = 0; nt < 4; nt++)
#pragma unroll
          for (int r = 0; r < 4; r++)
            Ps[wave][(mi * 16 + quad * 4 + r) * 72 + nt * 16 + l16] =
                __float2bfloat16(sc[mi][nt][r]);

#pragma unroll
      for (int mi = 0; mi < 2; mi++)
#pragma unroll
        for (int dt = 0; dt < 8; dt++)
#pragma unroll
          for (int r = 0; r < 4; r++)
            oacc[mi][dt][r] *= alpha[mi][r];

#pragma unroll
      for (int ks = 0; ks < 2; ks++) {
        short8 ap0 = *(const short8*)(&Ps[wave][(l16) * 72 + ks * 32 + quad * 8]);
        short8 ap1 = *(const short8*)(&Ps[wave][(16 + l16) * 72 + ks * 32 + quad * 8]);
#pragma unroll
        for (int dt = 0; dt < 8; dt++) {
          short8 bv = *(const short8*)(Vt + (dt * 16 + l16) * 72 + ks * 32 + quad * 8);
          oacc[0][dt] = __builtin_amdgcn_mfma_f32_16x16x32_bf16(ap0, bv, oacc[0][dt], 0, 0, 0);
          oacc[1][dt] = __builtin_amdgcn_mfma_f32_16x16x32_bf16(ap1, bv, oacc[1][dt], 0, 0, 0);
        }
      }
    }
  }

#pragma unroll
  for (int mi = 0; mi < 2; mi++)
#pragma unroll
    for (int r = 0; r < 4; r++) {
      const float inv = 1.0f / l_i[mi][r];
      const long s = q0 + wave * 32 + mi * 16 + quad * 4 + r;
#pragma unroll
      for (int dt = 0; dt < 8; dt++)
        Ob[s * 2048 + dt * 16 + l16] = __float2bfloat16(oacc[mi][dt][r] * inv);
    }
}

// ---------------------------------------------------------------------------
extern "C" void kernel_launch(void* const* d_in, const int* in_sizes, int n_in,
                              void* d_out, int out_size, void* d_ws, size_t ws_size,
                              hipStream_t stream) {
  const float* x  = (const float*)d_in[0];
  const float* wq = (const float*)d_in[1];
  const float* wk = (const float*)d_in[2];
  const float* wv = (const float*)d_in[3];
  const float* wo = (const float*)d_in[4];
  float* out = (float*)d_out;

  const int B = 2, S = 2048, D = 2048, H = 16;
  const int M = B * S;                    // 4096
  const long tsz = (long)M * D;           // 8.39M elems
  const long wsz = (long)D * D;           // 4.19M elems

  if (ws_size < 4 * (size_t)tsz * sizeof(bf16)) return;   // 67 MB

  bf16* qb  = (bf16*)d_ws;
  bf16* kb  = qb + tsz;
  bf16* vtb = kb + tsz;                   // transposed V: [b][h][d][s]
  bf16* ab  = vtb + tsz;

  // d_out as scratch: xb (tsz) + wq' (wsz) + wk' (wsz) = exactly out bytes.
  bf16* xb  = (bf16*)d_out;
  bf16* wqb = xb + tsz;
  bf16* wkb = wqb + wsz;
  bf16* wvb = ab;                         // front half of ab (dead until flash)
  floatx2* rtab = (floatx2*)(ab + wsz);   // 1 MB rope table in ab's back half
  bf16* wob = qb;                         // qb dead after flash

  cast_kernel<<<(int)(tsz / 8 / 256), 256, 0, stream>>>(x,  xb,  tsz);
  cast_kernel<<<(int)(wsz / 8 / 256), 256, 0, stream>>>(wq, wqb, wsz);
  cast_kernel<<<(int)(wsz / 8 / 256), 256, 0, stream>>>(wk, wkb, wsz);
  cast_kernel<<<(int)(wsz / 8 / 256), 256, 0, stream>>>(wv, wvb, wsz);
  rope_tab_kernel<<<(S * 64) / 256, 256, 0, stream>>>(rtab);

  qkv_gemm<<<dim3(M / 128, 24), 512, 0, stream>>>(
      xb, wqb, wkb, wvb, qb, kb, vtb, rtab, M, D, D);

  flash_attn<<<dim3(B * H, S / 128), 256, 0, stream>>>(qb, kb, vtb, ab, S);

  cast_kernel<<<(int)(wsz / 8 / 256), 256, 0, stream>>>(wo, wob, wsz);
  gemm_out<<<dim3(M / 128, D / 256), 512, 0, stream>>>(ab, wob, out, M, D, D);
}

// Round 5
// 421.275 us; speedup vs baseline: 1.1049x; 1.0095x over previous
//
// ---------------------------------------------------------------------------
// THEORY (Round 5)
// R4: qkv 143 us, MfmaUtil 31%, conflicts 0, grid fully round-quantized.
// 31% == the LDS-feed ceiling of a 64x64 wave tile: FLOP/LDS-byte =
// Mw*Nw/(Mw+Nw) = 32. The schedule is no longer the limiter; geometry is.
// m201 (verified 1563 TF / 62% MfmaUtil) uses a 128x64 wave tile (ratio 42.7),
// BK=64, per-half-K phase interleave, 2 barriers per K-tile.
//
// CHANGE (qkv only; gemm_out keeps the proven R4 core):
//   256x256 tile, BK=64, 8 waves (2Mx4N), wave tile 128x64, acc[8][4].
//   LDS: 2 buffers x (A 256x64 + B 256x64) = 128 KiB.
//   Staging in K-HALVES (256 rows x 32 k = 16 KB, 2 GLDS/thread) so the
//   dependence "phase -> staged half" is wave-uniform:
//     FIFO per K-tile: A-kh0, B-kh0, A-kh1, B-kh1 (staged during kt-1).
//     waits: vmcnt(4) at tile top (kh0 resident) and mid-tile (kh1 resident),
//     never 0 except the last tile's second half.
//   4 phases/K-tile: {8 ds_read | 2 GLDS | 16 MFMA}, {4 | 2 | 16}, x2 for kh1.
//   Swizzle: chunk' = chunk ^ ((row>>1)&3) (4x16B chunks per 64B row) on
//   global SOURCE + ds_read addr; LDS dest linear (rule 21). 2-way = free.
// PREDICTED: qkv 143 -> ~95 us, MfmaUtil 31 -> 50-60%, conflicts ~0,
// LDS 131072, total 425 -> ~375. flash_attn should appear in top-5 next.
// ---------------------------------------------------------------------------
#include <hip/hip_runtime.h>
#include <hip/hip_bf16.h>

using bf16 = __hip_bfloat16;
typedef __attribute__((ext_vector_type(8))) short short8;
typedef __attribute__((ext_vector_type(4))) float floatx4;
typedef __attribute__((ext_vector_type(2))) float floatx2;

#define GLDS16(g, l)                                                        \
  __builtin_amdgcn_global_load_lds(                                         \
      (const __attribute__((address_space(1))) void*)(g),                   \
      (__attribute__((address_space(3))) void*)(l), 16, 0, 0)

#define MFMA16(a, b, c) __builtin_amdgcn_mfma_f32_16x16x32_bf16(a, b, c, 0, 0, 0)

__device__ __forceinline__ short f2b(float x) {
  union { bf16 h; short s; } u;
  u.h = __float2bfloat16(x);
  return u.s;
}
__device__ __forceinline__ void st(float* p, float v) { *p = v; }
__device__ __forceinline__ void st(bf16* p, float v) { *p = __float2bfloat16(v); }

// ---- DPP cross-lane (stays off the LDS pipe) ------------------------------
template <int CTRL>
__device__ __forceinline__ float dpp_f(float x) {
  return __int_as_float(__builtin_amdgcn_update_dpp(
      0, __float_as_int(x), CTRL, 0xF, 0xF, true));
}
__device__ __forceinline__ float red16_max(float x) {
  x = fmaxf(x, dpp_f<0xB1>(x));    // quad_perm xor1
  x = fmaxf(x, dpp_f<0x4E>(x));    // quad_perm xor2
  x = fmaxf(x, dpp_f<0x141>(x));   // row_half_mirror
  x = fmaxf(x, dpp_f<0x140>(x));   // row_mirror
  return x;
}
__device__ __forceinline__ float red16_sum(float x) {
  x += dpp_f<0xB1>(x);
  x += dpp_f<0x4E>(x);
  x += dpp_f<0x141>(x);
  x += dpp_f<0x140>(x);
  return x;
}

// ---------------------------------------------------------------------------
// fp32 -> bf16 cast, 8 elems/thread, coalesced.
// ---------------------------------------------------------------------------
__global__ void cast_kernel(const float* __restrict__ in, bf16* __restrict__ out,
                            long n) {
  long i = ((long)blockIdx.x * blockDim.x + threadIdx.x) * 8;
  if (i >= n) return;
  floatx4 a = *(const floatx4*)(in + i);
  floatx4 b = *(const floatx4*)(in + i + 4);
  short8 r;
  r[0] = f2b(a[0]); r[1] = f2b(a[1]); r[2] = f2b(a[2]); r[3] = f2b(a[3]);
  r[4] = f2b(b[0]); r[5] = f2b(b[1]); r[6] = f2b(b[2]); r[7] = f2b(b[3]);
  *(short8*)(out + i) = r;
}

// ---------------------------------------------------------------------------
// RoPE cos/sin table: tab[s*64+p] = {cos(s*invf(p)), sin(s*invf(p))}.
// ---------------------------------------------------------------------------
__global__ void rope_tab_kernel(floatx2* __restrict__ tab) {
  const int t = blockIdx.x * blockDim.x + threadIdx.x;   // [0, 131072)
  const int s = t >> 6, p = t & 63;
  const float invf = exp2f(-(float)p * (13.287712379549449f / 64.0f));
  float sn, cs;
  sincosf((float)s * invf, &sn, &cs);
  floatx2 e; e[0] = cs; e[1] = sn;
  tab[t] = e;
}

// ---------------------------------------------------------------------------
// 256x256 / BK=64 deep-pipelined core, wave tile 128x64, acc[8][4].
// LDS layout per matrix: [buf][khalf][row 0..255][chunk 0..3]*8 bf16,
// elem off = buf*16384 + kh*8192 + row*32 + chunk*8; chunk XOR-swizzled.
// ---------------------------------------------------------------------------
__device__ __forceinline__ void gemm_core256(
    const bf16* __restrict__ A, const bf16* __restrict__ B, int K,
    long m0, long n0, bf16* As, bf16* Bs, floatx4 (&acc)[8][4])
{
  const int tid  = threadIdx.x;
  const int wave = tid >> 6;
  const int lane = tid & 63;
  const int quad = lane >> 4;
  const int l16  = lane & 15;
  const int wr = wave >> 2;     // 0..1 -> rows wr*128
  const int wc = wave & 3;      // 0..3 -> cols wc*64

  // staging: one K-half of one matrix = 256 rows x 4 chunks = 1024 chunks;
  // 2 chunks/thread. c = i*512 + tid; row = c>>2; lds chunk = c&3;
  // global chunk = (c&3) ^ ((c>>3)&3)  (inverse of read-side swizzle).
  long ga[2], gb[2];
  int soff[2];
#pragma unroll
  for (int i = 0; i < 2; i++) {
    const int c = i * 512 + tid;
    const int row = c >> 2;
    const int gch = (c & 3) ^ ((c >> 3) & 3);
    ga[i] = (m0 + row) * (long)K + gch * 8;
    gb[i] = (n0 + row) * (long)K + gch * 8;
    soff[i] = (i * 512 + wave * 64) * 8;   // wave-uniform base; +lane*8 implicit
  }

  // read-side swizzled chunk (elem offset): rows read are 16*x + l16 with
  // 16|x*16, so (row>>1)&3 = (l16>>1)&3 for every fragment.
  const int qs = (quad ^ ((l16 >> 1) & 3)) * 8;

#pragma unroll
  for (int mi = 0; mi < 8; mi++)
#pragma unroll
    for (int ni = 0; ni < 4; ni++) {
      floatx4 z = {0.f, 0.f, 0.f, 0.f};
      acc[mi][ni] = z;
    }

  const int NT = K >> 6;   // 64-wide K-tiles

  // prologue: stage kt=0 into buf0. FIFO: A-kh0(2), B-kh0(2), A-kh1(2), B-kh1(2)
#pragma unroll
  for (int kh = 0; kh < 2; kh++) {
    GLDS16(A + ga[0] + kh * 32, As + kh * 8192 + soff[0]);
    GLDS16(A + ga[1] + kh * 32, As + kh * 8192 + soff[1]);
    GLDS16(B + gb[0] + kh * 32, Bs + kh * 8192 + soff[0]);
    GLDS16(B + gb[1] + kh * 32, Bs + kh * 8192 + soff[1]);
  }

  for (int kt = 0; kt < NT; kt++) {
    const bf16* Ab = As + (kt & 1) * 16384;
    const bf16* Bb = Bs + (kt & 1) * 16384;
    bf16* An = As + ((kt + 1) & 1) * 16384;
    bf16* Bn = Bs + ((kt + 1) & 1) * 16384;
    const long nk = (long)(kt + 1) * 64;
    const bool pf = (kt + 1) < NT;

    // ================= K-half 0 =================
    // kt's A-kh0,B-kh0 are the 4 oldest in flight; 4 newer (kt's kh1) allowed.
    asm volatile("s_waitcnt vmcnt(4)" ::: "memory");
    __builtin_amdgcn_s_barrier();

    short8 a0[4], b0[4];
#pragma unroll
    for (int mi = 0; mi < 4; mi++)
      a0[mi] = *(const short8*)(Ab + (wr * 128 + mi * 16 + l16) * 32 + qs);
#pragma unroll
    for (int ni = 0; ni < 4; ni++)
      b0[ni] = *(const short8*)(Bb + (wc * 64 + ni * 16 + l16) * 32 + qs);
    if (pf) {                                  // stage kt+1 A-kh0
      GLDS16(A + ga[0] + nk, An + soff[0]);
      GLDS16(A + ga[1] + nk, An + soff[1]);
    }
    asm volatile("s_waitcnt lgkmcnt(0)" ::: "memory");
    __builtin_amdgcn_sched_barrier(0);
    __builtin_amdgcn_s_setprio(1);
#pragma unroll
    for (int mi = 0; mi < 4; mi++)
#pragma unroll
      for (int ni = 0; ni < 4; ni++)
        acc[mi][ni] = MFMA16(a0[mi], b0[ni], acc[mi][ni]);
    __builtin_amdgcn_s_setprio(0);

    short8 a1[4];
#pragma unroll
    for (int mi = 0; mi < 4; mi++)
      a1[mi] = *(const short8*)(Ab + (wr * 128 + (mi + 4) * 16 + l16) * 32 + qs);
    if (pf) {                                  // stage kt+1 B-kh0
      GLDS16(B + gb[0] + nk, Bn + soff[0]);
      GLDS16(B + gb[1] + nk, Bn + soff[1]);
    }
    asm volatile("s_waitcnt lgkmcnt(0)" ::: "memory");
    __builtin_amdgcn_sched_barrier(0);
    __builtin_amdgcn_s_setprio(1);
#pragma unroll
    for (int mi = 0; mi < 4; mi++)
#pragma unroll
      for (int ni = 0; ni < 4; ni++)
        acc[mi + 4][ni] = MFMA16(a1[mi], b0[ni], acc[mi + 4][ni]);
    __builtin_amdgcn_s_setprio(0);

    // ================= K-half 1 =================
    // kt's A-kh1,B-kh1 are oldest; 4 newer (kt+1's A0,B0) allowed if staged.
    if (pf) asm volatile("s_waitcnt vmcnt(4)" ::: "memory");
    else    asm volatile("s_waitcnt vmcnt(0)" ::: "memory");
    __builtin_amdgcn_s_barrier();

#pragma unroll
    for (int mi = 0; mi < 4; mi++)
      a0[mi] = *(const short8*)(Ab + 8192 + (wr * 128 + mi * 16 + l16) * 32 + qs);
#pragma unroll
    for (int ni = 0; ni < 4; ni++)
      b0[ni] = *(const short8*)(Bb + 8192 + (wc * 64 + ni * 16 + l16) * 32 + qs);
    if (pf) {                                  // stage kt+1 A-kh1
      GLDS16(A + ga[0] + nk + 32, An + 8192 + soff[0]);
      GLDS16(A + ga[1] + nk + 32, An + 8192 + soff[1]);
    }
    asm volatile("s_waitcnt lgkmcnt(0)" ::: "memory");
    __builtin_amdgcn_sched_barrier(0);
    __builtin_amdgcn_s_setprio(1);
#pragma unroll
    for (int mi = 0; mi < 4; mi++)
#pragma unroll
      for (int ni = 0; ni < 4; ni++)
        acc[mi][ni] = MFMA16(a0[mi], b0[ni], acc[mi][ni]);
    __builtin_amdgcn_s_setprio(0);

#pragma unroll
    for (int mi = 0; mi < 4; mi++)
      a1[mi] = *(const short8*)(Ab + 8192 + (wr * 128 + (mi + 4) * 16 + l16) * 32 + qs);
    if (pf) {                                  // stage kt+1 B-kh1
      GLDS16(B + gb[0] + nk + 32, Bn + 8192 + soff[0]);
      GLDS16(B + gb[1] + nk + 32, Bn + 8192 + soff[1]);
    }
    asm volatile("s_waitcnt lgkmcnt(0)" ::: "memory");
    __builtin_amdgcn_sched_barrier(0);
    __builtin_amdgcn_s_setprio(1);
#pragma unroll
    for (int mi = 0; mi < 4; mi++)
#pragma unroll
      for (int ni = 0; ni < 4; ni++)
        acc[mi + 4][ni] = MFMA16(a1[mi], b0[ni], acc[mi + 4][ni]);
    __builtin_amdgcn_s_setprio(0);
  }
}

// ---------------------------------------------------------------------------
// 128x256 core (R4, proven): used by gemm_out. acc[4][4], BK=32, 4-slot ring.
// ---------------------------------------------------------------------------
__device__ __forceinline__ void gemm_core128(
    const bf16* __restrict__ A, const bf16* __restrict__ B, int K,
    long m0, long n0, bf16* As, bf16* Bs, floatx4 (&acc)[4][4])
{
  const int tid  = threadIdx.x;
  const int wave = tid >> 6;
  const int lane = tid & 63;
  const int quad = lane >> 4;
  const int l16  = lane & 15;
  const int wr = wave >> 2;
  const int wc = wave & 3;

  const int arow = tid >> 2;
  const int acol = (tid & 3) ^ ((tid >> 3) & 3);
  const long gaoff = (m0 + arow) * (long)K + acol * 8;
  const int alds = wave * 512;
  long gb[2];
  int blds[2];
#pragma unroll
  for (int i = 0; i < 2; i++) {
    const int c = i * 512 + tid;
    const int row = c >> 2;
    const int col = (c & 3) ^ ((c >> 3) & 3);
    gb[i] = (n0 + row) * (long)K + col * 8;
    blds[i] = (i * 512 + wave * 64) * 8;
  }
  const int qs = (quad ^ ((l16 >> 1) & 3)) * 8;

#pragma unroll
  for (int mi = 0; mi < 4; mi++)
#pragma unroll
    for (int ni = 0; ni < 4; ni++) {
      floatx4 z = {0.f, 0.f, 0.f, 0.f};
      acc[mi][ni] = z;
    }

  const int NT = K >> 5;
#pragma unroll
  for (int t = 0; t < 3; t++) {
    GLDS16(A + gaoff + t * 32, As + t * 4096 + alds);
    GLDS16(B + gb[0] + t * 32, Bs + t * 8192 + blds[0]);
    GLDS16(B + gb[1] + t * 32, Bs + t * 8192 + blds[1]);
  }
  asm volatile("s_waitcnt vmcnt(6)" ::: "memory");
  __builtin_amdgcn_s_barrier();

  for (int t = 0; t < NT; t++) {
    const bf16* Ab = As + (t & 3) * 4096;
    const bf16* Bb = Bs + (t & 3) * 8192;
    const int pf = t + 3;

    short8 a[4], b[4];
#pragma unroll
    for (int mi = 0; mi < 4; mi++)
      a[mi] = *(const short8*)(Ab + (wr * 64 + mi * 16 + l16) * 32 + qs);
#pragma unroll
    for (int ni = 0; ni < 4; ni++)
      b[ni] = *(const short8*)(Bb + (wc * 64 + ni * 16 + l16) * 32 + qs);

    if (pf < NT) {
      bf16* Apf = As + (pf & 3) * 4096;
      bf16* Bpf = Bs + (pf & 3) * 8192;
      const long pfk = (long)pf * 32;
      GLDS16(A + gaoff + pfk, Apf + alds);
      GLDS16(B + gb[0] + pfk, Bpf + blds[0]);
      GLDS16(B + gb[1] + pfk, Bpf + blds[1]);
    }
    __builtin_amdgcn_s_barrier();
    asm volatile("s_waitcnt lgkmcnt(0)" ::: "memory");
    __builtin_amdgcn_sched_barrier(0);
    __builtin_amdgcn_s_setprio(1);
#pragma unroll
    for (int mi = 0; mi < 4; mi++)
#pragma unroll
      for (int ni = 0; ni < 4; ni++)
        acc[mi][ni] = MFMA16(a[mi], b[ni], acc[mi][ni]);
    __builtin_amdgcn_s_setprio(0);

    const int staged = (pf < NT) ? pf : (NT - 1);
    const int newer  = staged - t - 1;
    if (newer >= 2)       asm volatile("s_waitcnt vmcnt(6)" ::: "memory");
    else if (newer == 1)  asm volatile("s_waitcnt vmcnt(3)" ::: "memory");
    else                  asm volatile("s_waitcnt vmcnt(0)" ::: "memory");
    __builtin_amdgcn_s_barrier();
  }
}

// ---------------------------------------------------------------------------
// Fused QKV projection on the 256x256/BK=64 core.
// grid (M/256, 24): sel = y>>3 picks weight/output, n0 = (y&7)*256.
// 384 blocks = exactly 2 full rounds (1 block/CU at 128 KiB LDS).
// ---------------------------------------------------------------------------
__global__ __launch_bounds__(512, 2) void qkv_gemm(
    const bf16* __restrict__ A,
    const bf16* __restrict__ B0, const bf16* __restrict__ B1,
    const bf16* __restrict__ B2,
    bf16* __restrict__ C0, bf16* __restrict__ C1, bf16* __restrict__ Cvt,
    const floatx2* __restrict__ rtab,
    int M, int N, int K)
{
  __shared__ __align__(16) bf16 As[2 * 16384];
  __shared__ __align__(16) bf16 Bs[2 * 16384];

  const int sel = blockIdx.y >> 3;
  const long m0 = (long)blockIdx.x * 256;
  const long n0 = (long)(blockIdx.y & 7) * 256;
  const bf16* B = (sel == 0) ? B0 : ((sel == 1) ? B1 : B2);

  floatx4 acc[8][4];
  gemm_core256(A, B, K, m0, n0, As, Bs, acc);

  const int tid  = threadIdx.x;
  const int wave = tid >> 6;
  const int lane = tid & 63;
  const int quad = lane >> 4;
  const int l16  = lane & 15;
  const int wr = wave >> 2;
  const int wc = wave & 3;

  if (sel < 2) {
    // RoPE epilogue: pairs (2p,2p+1) in adjacent lanes (l16 bit0).
    bf16* C = (sel == 0) ? C0 : C1;
    const float sgn = (l16 & 1) ? 1.0f : -1.0f;
#pragma unroll
    for (int ni = 0; ni < 4; ni++) {
      const int n = (int)n0 + wc * 64 + ni * 16 + l16;   // h*128 + d
      const int p = (n & 127) >> 1;
#pragma unroll
      for (int mi = 0; mi < 8; mi++) {
        floatx4 v = acc[mi][ni];
        const int mbase = (int)m0 + wr * 128 + mi * 16 + quad * 4;
#pragma unroll
        for (int r = 0; r < 4; r++) {
          const int spos = (mbase + r) & 2047;
          const floatx2 cssn = rtab[spos * 64 + p];
          const float pv = dpp_f<0xB1>(v[r]);       // pair partner
          const float outv = v[r] * cssn[0] + pv * (sgn * cssn[1]);
          st(&C[(long)(mbase + r) * N + n], outv);
        }
      }
    }
  } else {
    // transposed V epilogue: v_t[((b*16+h)*128+d)*2048 + s], 4 s packed
#pragma unroll
    for (int ni = 0; ni < 4; ni++) {
      const int n = (int)n0 + wc * 64 + ni * 16 + l16;   // h*128 + d
      const int hh = n >> 7, d = n & 127;
#pragma unroll
      for (int mi = 0; mi < 8; mi++) {
        floatx4 v = acc[mi][ni];
        const int m = (int)m0 + wr * 128 + mi * 16 + quad * 4;
        const int bb = m >> 11, s = m & 2047;
        unsigned long long pk =
            (unsigned long long)(unsigned short)f2b(v[0]) |
            ((unsigned long long)(unsigned short)f2b(v[1]) << 16) |
            ((unsigned long long)(unsigned short)f2b(v[2]) << 32) |
            ((unsigned long long)(unsigned short)f2b(v[3]) << 48);
        *(unsigned long long*)(Cvt + ((long)((bb * 16 + hh) * 128 + d)) * 2048 + s) = pk;
      }
    }
  }
}

// ---------------------------------------------------------------------------
// Final projection GEMM (bf16 x bf16 -> fp32 out), R4 128x256 core.
// grid 32x8 = 256 blocks = exactly 1 full round.
// ---------------------------------------------------------------------------
__global__ __launch_bounds__(512, 2) void gemm_out(
    const bf16* __restrict__ A, const bf16* __restrict__ B,
    float* __restrict__ C, int M, int N, int K)
{
  __shared__ __align__(16) bf16 As[4 * 4096];
  __shared__ __align__(16) bf16 Bs[4 * 8192];
  const long m0 = (long)blockIdx.x * 128;
  const long n0 = (long)blockIdx.y * 256;

  floatx4 acc[4][4];
  gemm_core128(A, B, K, m0, n0, As, Bs, acc);

  const int tid  = threadIdx.x;
  const int wave = tid >> 6;
  const int lane = tid & 63;
  const int quad = lane >> 4;
  const int l16  = lane & 15;
  const int wr = wave >> 2;
  const int wc = wave & 3;

#pragma unroll
  for (int mi = 0; mi < 4; mi++)
#pragma unroll
    for (int ni = 0; ni < 4; ni++) {
      floatx4 v = acc[mi][ni];
      const long row = m0 + wr * 64 + mi * 16 + quad * 4;
      const long col = n0 + wc * 64 + ni * 16 + l16;
#pragma unroll
      for (int r = 0; r < 4; r++)
        C[(row + r) * (long)N + col] = v[r];
    }
}

// ---------------------------------------------------------------------------
// Causal flash attention (unchanged this round).
// ---------------------------------------------------------------------------
#define NEG_BIG (-30000.0f)

__global__ __launch_bounds__(256) void flash_attn(
    const bf16* __restrict__ q, const bf16* __restrict__ k,
    const bf16* __restrict__ vt, bf16* __restrict__ o, int S)
{
  __shared__ bf16 Ks[64 * 136];      // K tile row-major, stride 136
  __shared__ bf16 Vt[128 * 72];      // V^T tile: [d][kv], stride 72
  __shared__ bf16 Ps[4][32 * 72];    // per-wave P scratch, stride 72

  const int tid  = threadIdx.x;
  const int wave = tid >> 6;
  const int lane = tid & 63;
  const int quad = lane >> 4;
  const int l16  = lane & 15;

  const int bh = blockIdx.x;
  const int b  = bh >> 4, h = bh & 15;
  const int q0 = ((int)gridDim.y - 1 - (int)blockIdx.y) * 128;  // heavy first

  const bf16* Qb = q + ((long)b * S * 16 + h) * 128;
  const bf16* Kb = k + ((long)b * S * 16 + h) * 128;
  const bf16* Vg = vt + (long)bh * 128 * S;       // [d][s]
  bf16*       Ob = o + ((long)b * S * 16 + h) * 128;

  int kr[4], kc[4], vr[4], vc[4];
#pragma unroll
  for (int it = 0; it < 4; it++) {
    const int c = tid + it * 256;
    kr[it] = c >> 4;  kc[it] = (c & 15) * 8;   // K: 64 rows x 128 d
    vr[it] = c >> 3;  vc[it] = (c & 7) * 8;    // V^T: 128 d x 64 kv
  }

  short8 aq[2][4];
#pragma unroll
  for (int mi = 0; mi < 2; mi++)
#pragma unroll
    for (int kt = 0; kt < 4; kt++)
      aq[mi][kt] = *(const short8*)(
          Qb + (long)(q0 + wave * 32 + mi * 16 + l16) * 2048 + kt * 32 + quad * 8);

  float m_i[2][4], l_i[2][4];
  floatx4 oacc[2][8];
  const floatx4 zero4 = {0.f, 0.f, 0.f, 0.f};
#pragma unroll
  for (int mi = 0; mi < 2; mi++) {
#pragma unroll
    for (int r = 0; r < 4; r++) { m_i[mi][r] = NEG_BIG; l_i[mi][r] = 0.f; }
#pragma unroll
    for (int dt = 0; dt < 8; dt++) oacc[mi][dt] = zero4;
  }

  const float SCL2 = 0.08838834764831845f * 1.4426950408889634f;  // scale*log2e
  const int wrow0 = q0 + wave * 32;
  const int last  = q0 + 64;

  short8 kreg[4], vreg[4];
#pragma unroll
  for (int it = 0; it < 4; it++) {
    kreg[it] = *(const short8*)(Kb + (long)kr[it] * 2048 + kc[it]);
    vreg[it] = *(const short8*)(Vg + (long)vr[it] * S + vc[it]);
  }

  for (int kt0 = 0; kt0 <= last; kt0 += 64) {
    __syncthreads();

#pragma unroll
    for (int it = 0; it < 4; it++) {
      *(short8*)(Ks + kr[it] * 136 + kc[it]) = kreg[it];
      *(short8*)(Vt + vr[it] * 72 + vc[it]) = vreg[it];
    }
    __syncthreads();

    if (kt0 < last) {
      const int n0 = kt0 + 64;
#pragma unroll
      for (int it = 0; it < 4; it++) {
        kreg[it] = *(const short8*)(Kb + (long)(n0 + kr[it]) * 2048 + kc[it]);
        vreg[it] = *(const short8*)(Vg + (long)vr[it] * S + n0 + vc[it]);
      }
    }

    if (kt0 <= wrow0 + 31) {
      floatx4 sc[2][4];
#pragma unroll
      for (int mi = 0; mi < 2; mi++)
#pragma unroll
        for (int nt = 0; nt < 4; nt++) sc[mi][nt] = zero4;
#pragma unroll
      for (int nt = 0; nt < 4; nt++)
#pragma unroll
        for (int kt = 0; kt < 4; kt++) {
          short8 bk = *(const short8*)(Ks + (nt * 16 + l16) * 136 + kt * 32 + quad * 8);
          sc[0][nt] = __builtin_amdgcn_mfma_f32_16x16x32_bf16(aq[0][kt], bk, sc[0][nt], 0, 0, 0);
          sc[1][nt] = __builtin_amdgcn_mfma_f32_16x16x32_bf16(aq[1][kt], bk, sc[1][nt], 0, 0, 0);
        }

      const bool needmask = (kt0 + 63 > wrow0);
      float alpha[2][4];
#pragma unroll
      for (int mi = 0; mi < 2; mi++) {
#pragma unroll
        for (int r = 0; r < 4; r++) {
          const int qr = wrow0 + mi * 16 + quad * 4 + r;
          float mx = NEG_BIG;
          if (needmask) {
#pragma unroll
            for (int nt = 0; nt < 4; nt++) {
              const int kc2 = kt0 + nt * 16 + l16;
              float vsc = sc[mi][nt][r] * SCL2;
              vsc = (kc2 <= qr) ? vsc : NEG_BIG;
              sc[mi][nt][r] = vsc;
              mx = fmaxf(mx, vsc);
            }
          } else {
#pragma unroll
            for (int nt = 0; nt < 4; nt++) {
              float vsc = sc[mi][nt][r] * SCL2;
              sc[mi][nt][r] = vsc;
              mx = fmaxf(mx, vsc);
            }
          }
          mx = red16_max(mx);
          const float mnew = fmaxf(m_i[mi][r], mx);

          alpha[mi][r] = exp2f(m_i[mi][r] - mnew);
          float rs = 0.f;
#pragma unroll
          for (int nt = 0; nt < 4; nt++) {
            float p = exp2f(sc[mi][nt][r] - mnew);
            sc[mi][nt][r] = p;
            rs += p;
          }
          rs = red16_sum(rs);
          l_i[mi][r] = l_i[mi][r] * alpha[mi][r] + rs;
          m_i[mi][r] = mnew;
        }
      }

#pragma unroll
      for (int mi = 0; mi < 2; mi++)
#pragma unroll
        for (int nt = 0; nt < 4; nt++)
#pragma unroll
          for (int r = 0; r < 4; r++)
            Ps[wave][(mi * 16 + quad * 4 + r) * 72 + nt * 16 + l16] =
                __float2bfloat16(sc[mi][nt][r]);

#pragma unroll
      for (int mi = 0; mi < 2; mi++)
#pragma unroll
        for (int dt = 0; dt < 8; dt++)
#pragma unroll
          for (int r = 0; r < 4; r++)
            oacc[mi][dt][r] *= alpha[mi][r];

#pragma unroll
      for (int ks = 0; ks < 2; ks++) {
        short8 ap0 = *(const short8*)(&Ps[wave][(l16) * 72 + ks * 32 + quad * 8]);
        short8 ap1 = *(const short8*)(&Ps[wave][(16 + l16) * 72 + ks * 32 + quad * 8]);
#pragma unroll
        for (int dt = 0; dt < 8; dt++) {
          short8 bv = *(const short8*)(Vt + (dt * 16 + l16) * 72 + ks * 32 + quad * 8);
          oacc[0][dt] = __builtin_amdgcn_mfma_f32_16x16x32_bf16(ap0, bv, oacc[0][dt], 0, 0, 0);
          oacc[1][dt] = __builtin_amdgcn_mfma_f32_16x16x32_bf16(ap1, bv, oacc[1][dt], 0, 0, 0);
        }
      }
    }
  }

#pragma unroll
  for (int mi = 0; mi < 2; mi++)
#pragma unroll
    for (int r = 0; r < 4; r++) {
      const float inv = 1.0f / l_i[mi][r];
      const long s = q0 + wave * 32 + mi * 16 + quad * 4 + r;
#pragma unroll
      for (int dt = 0; dt < 8; dt++)
        Ob[s * 2048 + dt * 16 + l16] = __float2bfloat16(oacc[mi][dt][r] * inv);
    }
}

// ---------------------------------------------------------------------------
extern "C" void kernel_launch(void* const* d_in, const int* in_sizes, int n_in,
                              void* d_out, int out_size, void* d_ws, size_t ws_size,
                              hipStream_t stream) {
  const float* x  = (const float*)d_in[0];
  const float* wq = (const float*)d_in[1];
  const float* wk = (const float*)d_in[2];
  const float* wv = (const float*)d_in[3];
  const float* wo = (const float*)d_in[4];
  float* out = (float*)d_out;

  const int B = 2, S = 2048, D = 2048, H = 16;
  const int M = B * S;                    // 4096
  const long tsz = (long)M * D;           // 8.39M elems
  const long wsz = (long)D * D;           // 4.19M elems

  if (ws_size < 4 * (size_t)tsz * sizeof(bf16)) return;   // 67 MB

  bf16* qb  = (bf16*)d_ws;
  bf16* kb  = qb + tsz;
  bf16* vtb = kb + tsz;                   // transposed V: [b][h][d][s]
  bf16* ab  = vtb + tsz;

  // d_out as scratch: xb (tsz) + wq' (wsz) + wk' (wsz) = exactly out bytes.
  bf16* xb  = (bf16*)d_out;
  bf16* wqb = xb + tsz;
  bf16* wkb = wqb + wsz;
  bf16* wvb = ab;                         // front half of ab (dead until flash)
  floatx2* rtab = (floatx2*)(ab + wsz);   // 1 MB rope table in ab's back half
  bf16* wob = qb;                         // qb dead after flash

  cast_kernel<<<(int)(tsz / 8 / 256), 256, 0, stream>>>(x,  xb,  tsz);
  cast_kernel<<<(int)(wsz / 8 / 256), 256, 0, stream>>>(wq, wqb, wsz);
  cast_kernel<<<(int)(wsz / 8 / 256), 256, 0, stream>>>(wk, wkb, wsz);
  cast_kernel<<<(int)(wsz / 8 / 256), 256, 0, stream>>>(wv, wvb, wsz);
  rope_tab_kernel<<<(S * 64) / 256, 256, 0, stream>>>(rtab);

  qkv_gemm<<<dim3(M / 256, 24), 512, 0, stream>>>(
      xb, wqb, wkb, wvb, qb, kb, vtb, rtab, M, D, D);

  flash_attn<<<dim3(B * H, S / 128), 256, 0, stream>>>(qb, kb, vtb, ab, S);

  cast_kernel<<<(int)(wsz / 8 / 256), 256, 0, stream>>>(wo, wob, wsz);
  gemm_out<<<dim3(M / 128, D / 256), 512, 0, stream>>>(ab, wob, out, M, D, D);
}

// Round 6
// 412.453 us; speedup vs baseline: 1.1285x; 1.0214x over previous
//
// ---------------------------------------------------------------------------
// THEORY (Round 6)
// R5 post-mortem: MfmaUtil stuck at 31% because (a) 384 blocks @ 1 block/CU
// = 1.5 rounds (25% idle), (b) barrier-lockstep serializes LDS and MFMA:
// per-K-tile cycles = LDS(2310) + MFMA(2480) + overhead = 5980 measured,
// i.e. ZERO pipe overlap. Intra-block pipelining is a proven dead end
// (m131-m141); independent waves overlap fully (m114).
//
// CHANGE: both GEMMs -> 256-thread blocks (4 waves, 2Mx2N), wave tile 128x64
// (keeps the 42.7 FLOP/LDS-byte ratio), BM=256 BN=128 BK=32, ring-3 LDS
// (72 KiB) -> TWO blocks co-resident per CU; their phase drift overlaps one
// block's MFMA with the other's ds_reads. One barrier + vmcnt(6) + 12 ds_read
// + 6 GLDS + 32 MFMA per K-step. Same zero-conflict swizzle.
// Grids: qkv 16x48=768 (3 blocks/CU, 2 resident); gemm_out 16x16=256 (1 round).
// PREDICTED: qkv 136 -> 85-95 us, MfmaUtil 31 -> 45-60%, LDS 73728,
// occupancy ~25%, conflicts 0; gemm_out ~35-45 us; total 421 -> ~300-320.
// flash_attn enters top-5 -> counters for next round.
// ---------------------------------------------------------------------------
#include <hip/hip_runtime.h>
#include <hip/hip_bf16.h>

using bf16 = __hip_bfloat16;
typedef __attribute__((ext_vector_type(8))) short short8;
typedef __attribute__((ext_vector_type(4))) float floatx4;
typedef __attribute__((ext_vector_type(2))) float floatx2;

#define GLDS16(g, l)                                                        \
  __builtin_amdgcn_global_load_lds(                                         \
      (const __attribute__((address_space(1))) void*)(g),                   \
      (__attribute__((address_space(3))) void*)(l), 16, 0, 0)

#define MFMA16(a, b, c) __builtin_amdgcn_mfma_f32_16x16x32_bf16(a, b, c, 0, 0, 0)

__device__ __forceinline__ short f2b(float x) {
  union { bf16 h; short s; } u;
  u.h = __float2bfloat16(x);
  return u.s;
}
__device__ __forceinline__ void st(float* p, float v) { *p = v; }
__device__ __forceinline__ void st(bf16* p, float v) { *p = __float2bfloat16(v); }

// ---- DPP cross-lane (stays off the LDS pipe) ------------------------------
template <int CTRL>
__device__ __forceinline__ float dpp_f(float x) {
  return __int_as_float(__builtin_amdgcn_update_dpp(
      0, __float_as_int(x), CTRL, 0xF, 0xF, true));
}
__device__ __forceinline__ float red16_max(float x) {
  x = fmaxf(x, dpp_f<0xB1>(x));    // quad_perm xor1
  x = fmaxf(x, dpp_f<0x4E>(x));    // quad_perm xor2
  x = fmaxf(x, dpp_f<0x141>(x));   // row_half_mirror
  x = fmaxf(x, dpp_f<0x140>(x));   // row_mirror
  return x;
}
__device__ __forceinline__ float red16_sum(float x) {
  x += dpp_f<0xB1>(x);
  x += dpp_f<0x4E>(x);
  x += dpp_f<0x141>(x);
  x += dpp_f<0x140>(x);
  return x;
}

// ---------------------------------------------------------------------------
// fp32 -> bf16 cast, 8 elems/thread, coalesced.
// ---------------------------------------------------------------------------
__global__ void cast_kernel(const float* __restrict__ in, bf16* __restrict__ out,
                            long n) {
  long i = ((long)blockIdx.x * blockDim.x + threadIdx.x) * 8;
  if (i >= n) return;
  floatx4 a = *(const floatx4*)(in + i);
  floatx4 b = *(const floatx4*)(in + i + 4);
  short8 r;
  r[0] = f2b(a[0]); r[1] = f2b(a[1]); r[2] = f2b(a[2]); r[3] = f2b(a[3]);
  r[4] = f2b(b[0]); r[5] = f2b(b[1]); r[6] = f2b(b[2]); r[7] = f2b(b[3]);
  *(short8*)(out + i) = r;
}

// ---------------------------------------------------------------------------
// RoPE cos/sin table: tab[s*64+p] = {cos(s*invf(p)), sin(s*invf(p))}.
// ---------------------------------------------------------------------------
__global__ void rope_tab_kernel(floatx2* __restrict__ tab) {
  const int t = blockIdx.x * blockDim.x + threadIdx.x;   // [0, 131072)
  const int s = t >> 6, p = t & 63;
  const float invf = exp2f(-(float)p * (13.287712379549449f / 64.0f));
  float sn, cs;
  sincosf((float)s * invf, &sn, &cs);
  floatx2 e; e[0] = cs; e[1] = sn;
  tab[t] = e;
}

// ---------------------------------------------------------------------------
// 256x128 / BK=32 core, 256 threads = 4 waves (2Mx2N), wave tile 128x64,
// acc[8][4]. Ring-3 LDS: slot = t%3; A slot 8192 el (256x32), B slot 4096 el
// (128x32); total 72 KiB -> 2 blocks/CU. Per K-step: vmcnt(6) -> barrier ->
// 12 ds_read_b128 | 6 GLDS16 (t+2) -> lgkm(0) -> setprio(1) -> 32 MFMA.
// Swizzle: 16B-chunk' = chunk ^ ((row>>1)&3) on global SOURCE + ds_read addr;
// LDS dest linear (rule 21). Measured 0 conflicts (R4/R5, same algebra).
// ---------------------------------------------------------------------------
__device__ __forceinline__ void gemm_core(
    const bf16* __restrict__ A, const bf16* __restrict__ B, int K,
    long m0, long n0, bf16* As, bf16* Bs, floatx4 (&acc)[8][4])
{
  const int tid  = threadIdx.x;
  const int wave = tid >> 6;
  const int lane = tid & 63;
  const int quad = lane >> 4;
  const int l16  = lane & 15;
  const int wr = wave >> 1;     // 0..1 -> rows wr*128
  const int wc = wave & 1;      // 0..1 -> cols wc*64

  // A staging: 256 rows x 4 chunks = 1024 chunks, 4/thread.
  // B staging: 128 rows x 4 chunks = 512 chunks, 2/thread.
  // c -> row = c>>2, lds chunk = c&3, global chunk = (c&3)^((c>>3)&3).
  long ga[4];
  int aoff[4];
#pragma unroll
  for (int i = 0; i < 4; i++) {
    const int c = i * 256 + tid;
    const int row = c >> 2;
    const int gch = (c & 3) ^ ((c >> 3) & 3);
    ga[i] = (m0 + row) * (long)K + gch * 8;
    aoff[i] = (i * 256 + wave * 64) * 8;     // wave-uniform; +lane*16B in HW
  }
  long gb[2];
  int boff[2];
#pragma unroll
  for (int i = 0; i < 2; i++) {
    const int c = i * 256 + tid;
    const int row = c >> 2;
    const int gch = (c & 3) ^ ((c >> 3) & 3);
    gb[i] = (n0 + row) * (long)K + gch * 8;
    boff[i] = (i * 256 + wave * 64) * 8;
  }

  // read-side swizzled chunk: rows read are 16*x + l16 -> (row>>1)&3 = (l16>>1)&3
  const int qs = (quad ^ ((l16 >> 1) & 3)) * 8;

#pragma unroll
  for (int mi = 0; mi < 8; mi++)
#pragma unroll
    for (int ni = 0; ni < 4; ni++) {
      floatx4 z = {0.f, 0.f, 0.f, 0.f};
      acc[mi][ni] = z;
    }

  const int NT = K >> 5;

  // prologue: stage steps 0,1 into slots 0,1 (6 loads each; 12 in flight)
#pragma unroll
  for (int t = 0; t < 2; t++) {
    bf16* Ad = As + t * 8192;
    bf16* Bd = Bs + t * 4096;
    const long kk = (long)t * 32;
#pragma unroll
    for (int i = 0; i < 4; i++) GLDS16(A + ga[i] + kk, Ad + aoff[i]);
#pragma unroll
    for (int i = 0; i < 2; i++) GLDS16(B + gb[i] + kk, Bd + boff[i]);
  }

  int sl = 0;                    // slot of step t
  for (int t = 0; t < NT; t++) {
    // retire step t's 6 loads (t+1's 6 may stay in flight), then sync.
    if (t < NT - 1) asm volatile("s_waitcnt vmcnt(6)" ::: "memory");
    else            asm volatile("s_waitcnt vmcnt(0)" ::: "memory");
    __builtin_amdgcn_s_barrier();

    const bf16* Ab = As + sl * 8192;
    const bf16* Bb = Bs + sl * 4096;

    short8 a[8], b[4];
#pragma unroll
    for (int mi = 0; mi < 8; mi++)
      a[mi] = *(const short8*)(Ab + (wr * 128 + mi * 16 + l16) * 32 + qs);
#pragma unroll
    for (int ni = 0; ni < 4; ni++)
      b[ni] = *(const short8*)(Bb + (wc * 64 + ni * 16 + l16) * 32 + qs);

    if (t + 2 < NT) {            // stage step t+2 into slot (t+2)%3
      int s2 = sl + 2; if (s2 >= 3) s2 -= 3;
      bf16* Ad = As + s2 * 8192;
      bf16* Bd = Bs + s2 * 4096;
      const long kk = (long)(t + 2) * 32;
#pragma unroll
      for (int i = 0; i < 4; i++) GLDS16(A + ga[i] + kk, Ad + aoff[i]);
#pragma unroll
      for (int i = 0; i < 2; i++) GLDS16(B + gb[i] + kk, Bd + boff[i]);
    }

    asm volatile("s_waitcnt lgkmcnt(0)" ::: "memory");
    __builtin_amdgcn_sched_barrier(0);
    __builtin_amdgcn_s_setprio(1);
#pragma unroll
    for (int mi = 0; mi < 8; mi++)
#pragma unroll
      for (int ni = 0; ni < 4; ni++)
        acc[mi][ni] = MFMA16(a[mi], b[ni], acc[mi][ni]);
    __builtin_amdgcn_s_setprio(0);

    sl++; if (sl >= 3) sl = 0;
  }
}

// ---------------------------------------------------------------------------
// Fused QKV projection. grid (16, 48): sel = y>>4 picks weight/output,
// n0 = (y&15)*128, m0 = x*256. 768 blocks, 2 co-resident/CU.
// ---------------------------------------------------------------------------
__global__ __launch_bounds__(256, 2) void qkv_gemm(
    const bf16* __restrict__ A,
    const bf16* __restrict__ B0, const bf16* __restrict__ B1,
    const bf16* __restrict__ B2,
    bf16* __restrict__ C0, bf16* __restrict__ C1, bf16* __restrict__ Cvt,
    const floatx2* __restrict__ rtab,
    int M, int N, int K)
{
  __shared__ __align__(16) bf16 As[3 * 8192];
  __shared__ __align__(16) bf16 Bs[3 * 4096];

  const int sel = blockIdx.y >> 4;
  const long m0 = (long)blockIdx.x * 256;
  const long n0 = (long)(blockIdx.y & 15) * 128;
  const bf16* B = (sel == 0) ? B0 : ((sel == 1) ? B1 : B2);

  floatx4 acc[8][4];
  gemm_core(A, B, K, m0, n0, As, Bs, acc);

  const int tid  = threadIdx.x;
  const int wave = tid >> 6;
  const int lane = tid & 63;
  const int quad = lane >> 4;
  const int l16  = lane & 15;
  const int wr = wave >> 1;
  const int wc = wave & 1;

  if (sel < 2) {
    // RoPE epilogue: pairs (2p,2p+1) in adjacent lanes (l16 bit0).
    bf16* C = (sel == 0) ? C0 : C1;
    const float sgn = (l16 & 1) ? 1.0f : -1.0f;
#pragma unroll
    for (int ni = 0; ni < 4; ni++) {
      const int n = (int)n0 + wc * 64 + ni * 16 + l16;   // h*128 + d
      const int p = (n & 127) >> 1;
#pragma unroll
      for (int mi = 0; mi < 8; mi++) {
        floatx4 v = acc[mi][ni];
        const int mbase = (int)m0 + wr * 128 + mi * 16 + quad * 4;
#pragma unroll
        for (int r = 0; r < 4; r++) {
          const int spos = (mbase + r) & 2047;
          const floatx2 cssn = rtab[spos * 64 + p];
          const float pv = dpp_f<0xB1>(v[r]);       // pair partner
          const float outv = v[r] * cssn[0] + pv * (sgn * cssn[1]);
          st(&C[(long)(mbase + r) * N + n], outv);
        }
      }
    }
  } else {
    // transposed V epilogue: v_t[((b*16+h)*128+d)*2048 + s], 4 s packed
#pragma unroll
    for (int ni = 0; ni < 4; ni++) {
      const int n = (int)n0 + wc * 64 + ni * 16 + l16;   // h*128 + d
      const int hh = n >> 7, d = n & 127;
#pragma unroll
      for (int mi = 0; mi < 8; mi++) {
        floatx4 v = acc[mi][ni];
        const int m = (int)m0 + wr * 128 + mi * 16 + quad * 4;
        const int bb = m >> 11, s = m & 2047;
        unsigned long long pk =
            (unsigned long long)(unsigned short)f2b(v[0]) |
            ((unsigned long long)(unsigned short)f2b(v[1]) << 16) |
            ((unsigned long long)(unsigned short)f2b(v[2]) << 32) |
            ((unsigned long long)(unsigned short)f2b(v[3]) << 48);
        *(unsigned long long*)(Cvt + ((long)((bb * 16 + hh) * 128 + d)) * 2048 + s) = pk;
      }
    }
  }
}

// ---------------------------------------------------------------------------
// Final projection GEMM (bf16 x bf16 -> fp32 out), same core.
// grid (16,16) = 256 blocks = exactly 1 full round.
// ---------------------------------------------------------------------------
__global__ __launch_bounds__(256, 2) void gemm_out(
    const bf16* __restrict__ A, const bf16* __restrict__ B,
    float* __restrict__ C, int M, int N, int K)
{
  __shared__ __align__(16) bf16 As[3 * 8192];
  __shared__ __align__(16) bf16 Bs[3 * 4096];
  const long m0 = (long)blockIdx.x * 256;
  const long n0 = (long)blockIdx.y * 128;

  floatx4 acc[8][4];
  gemm_core(A, B, K, m0, n0, As, Bs, acc);

  const int tid  = threadIdx.x;
  const int wave = tid >> 6;
  const int lane = tid & 63;
  const int quad = lane >> 4;
  const int l16  = lane & 15;
  const int wr = wave >> 1;
  const int wc = wave & 1;

#pragma unroll
  for (int mi = 0; mi < 8; mi++)
#pragma unroll
    for (int ni = 0; ni < 4; ni++) {
      floatx4 v = acc[mi][ni];
      const long row = m0 + wr * 128 + mi * 16 + quad * 4;
      const long col = n0 + wc * 64 + ni * 16 + l16;
#pragma unroll
      for (int r = 0; r < 4; r++)
        C[(row + r) * (long)N + col] = v[r];
    }
}

// ---------------------------------------------------------------------------
// Causal flash attention (unchanged this round).
// ---------------------------------------------------------------------------
#define NEG_BIG (-30000.0f)

__global__ __launch_bounds__(256) void flash_attn(
    const bf16* __restrict__ q, const bf16* __restrict__ k,
    const bf16* __restrict__ vt, bf16* __restrict__ o, int S)
{
  __shared__ bf16 Ks[64 * 136];      // K tile row-major, stride 136
  __shared__ bf16 Vt[128 * 72];      // V^T tile: [d][kv], stride 72
  __shared__ bf16 Ps[4][32 * 72];    // per-wave P scratch, stride 72

  const int tid  = threadIdx.x;
  const int wave = tid >> 6;
  const int lane = tid & 63;
  const int quad = lane >> 4;
  const int l16  = lane & 15;

  const int bh = blockIdx.x;
  const int b  = bh >> 4, h = bh & 15;
  const int q0 = ((int)gridDim.y - 1 - (int)blockIdx.y) * 128;  // heavy first

  const bf16* Qb = q + ((long)b * S * 16 + h) * 128;
  const bf16* Kb = k + ((long)b * S * 16 + h) * 128;
  const bf16* Vg = vt + (long)bh * 128 * S;       // [d][s]
  bf16*       Ob = o + ((long)b * S * 16 + h) * 128;

  int kr[4], kc[4], vr[4], vc[4];
#pragma unroll
  for (int it = 0; it < 4; it++) {
    const int c = tid + it * 256;
    kr[it] = c >> 4;  kc[it] = (c & 15) * 8;   // K: 64 rows x 128 d
    vr[it] = c >> 3;  vc[it] = (c & 7) * 8;    // V^T: 128 d x 64 kv
  }

  short8 aq[2][4];
#pragma unroll
  for (int mi = 0; mi < 2; mi++)
#pragma unroll
    for (int kt = 0; kt < 4; kt++)
      aq[mi][kt] = *(const short8*)(
          Qb + (long)(q0 + wave * 32 + mi * 16 + l16) * 2048 + kt * 32 + quad * 8);

  float m_i[2][4], l_i[2][4];
  floatx4 oacc[2][8];
  const floatx4 zero4 = {0.f, 0.f, 0.f, 0.f};
#pragma unroll
  for (int mi = 0; mi < 2; mi++) {
#pragma unroll
    for (int r = 0; r < 4; r++) { m_i[mi][r] = NEG_BIG; l_i[mi][r] = 0.f; }
#pragma unroll
    for (int dt = 0; dt < 8; dt++) oacc[mi][dt] = zero4;
  }

  const float SCL2 = 0.08838834764831845f * 1.4426950408889634f;  // scale*log2e
  const int wrow0 = q0 + wave * 32;
  const int last  = q0 + 64;

  short8 kreg[4], vreg[4];
#pragma unroll
  for (int it = 0; it < 4; it++) {
    kreg[it] = *(const short8*)(Kb + (long)kr[it] * 2048 + kc[it]);
    vreg[it] = *(const short8*)(Vg + (long)vr[it] * S + vc[it]);
  }

  for (int kt0 = 0; kt0 <= last; kt0 += 64) {
    __syncthreads();

#pragma unroll
    for (int it = 0; it < 4; it++) {
      *(short8*)(Ks + kr[it] * 136 + kc[it]) = kreg[it];
      *(short8*)(Vt + vr[it] * 72 + vc[it]) = vreg[it];
    }
    __syncthreads();

    if (kt0 < last) {
      const int n0 = kt0 + 64;
#pragma unroll
      for (int it = 0; it < 4; it++) {
        kreg[it] = *(const short8*)(Kb + (long)(n0 + kr[it]) * 2048 + kc[it]);
        vreg[it] = *(const short8*)(Vg + (long)vr[it] * S + n0 + vc[it]);
      }
    }

    if (kt0 <= wrow0 + 31) {
      floatx4 sc[2][4];
#pragma unroll
      for (int mi = 0; mi < 2; mi++)
#pragma unroll
        for (int nt = 0; nt < 4; nt++) sc[mi][nt] = zero4;
#pragma unroll
      for (int nt = 0; nt < 4; nt++)
#pragma unroll
        for (int kt = 0; kt < 4; kt++) {
          short8 bk = *(const short8*)(Ks + (nt * 16 + l16) * 136 + kt * 32 + quad * 8);
          sc[0][nt] = __builtin_amdgcn_mfma_f32_16x16x32_bf16(aq[0][kt], bk, sc[0][nt], 0, 0, 0);
          sc[1][nt] = __builtin_amdgcn_mfma_f32_16x16x32_bf16(aq[1][kt], bk, sc[1][nt], 0, 0, 0);
        }

      const bool needmask = (kt0 + 63 > wrow0);
      float alpha[2][4];
#pragma unroll
      for (int mi = 0; mi < 2; mi++) {
#pragma unroll
        for (int r = 0; r < 4; r++) {
          const int qr = wrow0 + mi * 16 + quad * 4 + r;
          float mx = NEG_BIG;
          if (needmask) {
#pragma unroll
            for (int nt = 0; nt < 4; nt++) {
              const int kc2 = kt0 + nt * 16 + l16;
              float vsc = sc[mi][nt][r] * SCL2;
              vsc = (kc2 <= qr) ? vsc : NEG_BIG;
              sc[mi][nt][r] = vsc;
              mx = fmaxf(mx, vsc);
            }
          } else {
#pragma unroll
            for (int nt = 0; nt < 4; nt++) {
              float vsc = sc[mi][nt][r] * SCL2;
              sc[mi][nt][r] = vsc;
              mx = fmaxf(mx, vsc);
            }
          }
          mx = red16_max(mx);
          const float mnew = fmaxf(m_i[mi][r], mx);

          alpha[mi][r] = exp2f(m_i[mi][r] - mnew);
          float rs = 0.f;
#pragma unroll
          for (int nt = 0; nt < 4; nt++) {
            float p = exp2f(sc[mi][nt][r] - mnew);
            sc[mi][nt][r] = p;
            rs += p;
          }
          rs = red16_sum(rs);
          l_i[mi][r] = l_i[mi][r] * alpha[mi][r] + rs;
          m_i[mi][r] = mnew;
        }
      }

#pragma unroll
      for (int mi = 0; mi < 2; mi++)
#pragma unroll
        for (int nt = 0; nt < 4; nt++)
#pragma unroll
          for (int r = 0; r < 4; r++)
            Ps[wave][(mi * 16 + quad * 4 + r) * 72 + nt * 16 + l16] =
                __float2bfloat16(sc[mi][nt][r]);

#pragma unroll
      for (int mi = 0; mi < 2; mi++)
#pragma unroll
        for (int dt = 0; dt < 8; dt++)
#pragma unroll
          for (int r = 0; r < 4; r++)
            oacc[mi][dt][r] *= alpha[mi][r];

#pragma unroll
      for (int ks = 0; ks < 2; ks++) {
        short8 ap0 = *(const short8*)(&Ps[wave][(l16) * 72 + ks * 32 + quad * 8]);
        short8 ap1 = *(const short8*)(&Ps[wave][(16 + l16) * 72 + ks * 32 + quad * 8]);
#pragma unroll
        for (int dt = 0; dt < 8; dt++) {
          short8 bv = *(const short8*)(Vt + (dt * 16 + l16) * 72 + ks * 32 + quad * 8);
          oacc[0][dt] = __builtin_amdgcn_mfma_f32_16x16x32_bf16(ap0, bv, oacc[0][dt], 0, 0, 0);
          oacc[1][dt] = __builtin_amdgcn_mfma_f32_16x16x32_bf16(ap1, bv, oacc[1][dt], 0, 0, 0);
        }
      }
    }
  }

#pragma unroll
  for (int mi = 0; mi < 2; mi++)
#pragma unroll
    for (int r = 0; r < 4; r++) {
      const float inv = 1.0f / l_i[mi][r];
      const long s = q0 + wave * 32 + mi * 16 + quad * 4 + r;
#pragma unroll
      for (int dt = 0; dt < 8; dt++)
        Ob[s * 2048 + dt * 16 + l16] = __float2bfloat16(oacc[mi][dt][r] * inv);
    }
}

// ---------------------------------------------------------------------------
extern "C" void kernel_launch(void* const* d_in, const int* in_sizes, int n_in,
                              void* d_out, int out_size, void* d_ws, size_t ws_size,
                              hipStream_t stream) {
  const float* x  = (const float*)d_in[0];
  const float* wq = (const float*)d_in[1];
  const float* wk = (const float*)d_in[2];
  const float* wv = (const float*)d_in[3];
  const float* wo = (const float*)d_in[4];
  float* out = (float*)d_out;

  const int B = 2, S = 2048, D = 2048, H = 16;
  const int M = B * S;                    // 4096
  const long tsz = (long)M * D;           // 8.39M elems
  const long wsz = (long)D * D;           // 4.19M elems

  if (ws_size < 4 * (size_t)tsz * sizeof(bf16)) return;   // 67 MB

  bf16* qb  = (bf16*)d_ws;
  bf16* kb  = qb + tsz;
  bf16* vtb = kb + tsz;                   // transposed V: [b][h][d][s]
  bf16* ab  = vtb + tsz;

  // d_out as scratch: xb (tsz) + wq' (wsz) + wk' (wsz) = exactly out bytes.
  bf16* xb  = (bf16*)d_out;
  bf16* wqb = xb + tsz;
  bf16* wkb = wqb + wsz;
  bf16* wvb = ab;                         // front half of ab (dead until flash)
  floatx2* rtab = (floatx2*)(ab + wsz);   // 1 MB rope table in ab's back half
  bf16* wob = qb;                         // qb dead after flash

  cast_kernel<<<(int)(tsz / 8 / 256), 256, 0, stream>>>(x,  xb,  tsz);
  cast_kernel<<<(int)(wsz / 8 / 256), 256, 0, stream>>>(wq, wqb, wsz);
  cast_kernel<<<(int)(wsz / 8 / 256), 256, 0, stream>>>(wk, wkb, wsz);
  cast_kernel<<<(int)(wsz / 8 / 256), 256, 0, stream>>>(wv, wvb, wsz);
  rope_tab_kernel<<<(S * 64) / 256, 256, 0, stream>>>(rtab);

  qkv_gemm<<<dim3(16, 48), 256, 0, stream>>>(
      xb, wqb, wkb, wvb, qb, kb, vtb, rtab, M, D, D);

  flash_attn<<<dim3(B * H, S / 128), 256, 0, stream>>>(qb, kb, vtb, ab, S);

  cast_kernel<<<(int)(wsz / 8 / 256), 256, 0, stream>>>(wo, wob, wsz);
  gemm_out<<<dim3(16, 16), 256, 0, stream>>>(ab, wob, out, M, D, D);
}